// Round 20
// baseline (1212.222 us; speedup 1.0000x reference)
//
#include <hip/hip_runtime.h>

#define N_NODES 100000
#define N_EDGES 3200000
#define F_IN    1433
#define HID     16
#define N_CLS   7
#define NWINT   48                                   // K windows of 32 (K padded to 1536)
#define NWIN    12                                   // windows per wave (4 waves)
#define GB1     (N_NODES / 16)                       // 6250 gemm tiles
#define ROWBLKS ((N_NODES + 255) / 256)              // 391
#define XB_STRIDE 1440                               // padded bf16 row (2880B, 16B-aligned)
#define XB_TOTAL  ((size_t)N_NODES * XB_STRIDE)
#define NF4     (N_NODES * F_IN / 4)                 // 35,825,000 float4s (exact)
#define PBR     2048                                 // repack blocks (grid-stride)
#define QBLK    (N_EDGES / 4 / 256)                  // 3125 fill blocks (exact quads)
#define NBKT    256                                  // coarse buckets
#define NPBK    391                                  // nodes per bucket (256*391=100096)
#define BCAP2   2048                                 // cap per (partition,bucket); mean 1563 +12σ
#define SRCM    0x1FFFF                              // 17-bit src mask

typedef __attribute__((ext_vector_type(8))) short short8v;
typedef __attribute__((ext_vector_type(4))) float float4v;

__device__ __forceinline__ unsigned short f2bf(float f) {
    unsigned u = __float_as_uint(f);
    u += 0x7fffu + ((u >> 16) & 1u);                 // RNE
    return (unsigned short)(u >> 16);
}

// ---------------- prep: pre-swizzled bf16 W1 fragments ----------------
__global__ void prep_w1_kernel(const float* __restrict__ W1, short* __restrict__ w1f) {
    int w = blockIdx.x;
    int l = threadIdx.x;
    int col = l & 15;
    int kb = w * 32 + (l >> 4) * 8;
    short8v f;
#pragma unroll
    for (int i = 0; i < 8; ++i) {
        int k = kb + i;
        float v = (k < F_IN) ? W1[k * HID + col] : 0.f;
        f[i] = (short)f2bf(v);
    }
    *(short8v*)(w1f + ((size_t)w * 64 + l) * 8) = f;
}

// ---------------- x -> bf16 repack (R13-proven ~150us) ----------------
__global__ __launch_bounds__(256) void repack_kernel(const float* __restrict__ x,
                                                     short* __restrict__ xb) {
    const int bid = blockIdx.x;
    for (long i4 = (long)bid * 256 + threadIdx.x; i4 < NF4; i4 += (long)PBR * 256) {
        float4 v = ((const float4*)x)[i4];
        float fv[4] = {v.x, v.y, v.z, v.w};
        unsigned e0 = (unsigned)(i4 * 4);
#pragma unroll
        for (int j = 0; j < 4; ++j) {
            unsigned e = e0 + j;
            unsigned row = e / 1433u;                 // magic-mul
            unsigned col = e - row * 1433u;
            xb[(size_t)row * XB_STRIDE + col] = (short)f2bf(fv[j]);
        }
    }
    for (int p = bid * 256 + threadIdx.x; p < N_NODES * 7; p += PBR * 256) {
        int row = p / 7;
        int col = 1433 + (p - row * 7);
        xb[(size_t)row * XB_STRIDE + col] = 0;
    }
}

// ---------------- bucket fill: XCD-private 8x256 coarse buckets ----------
// Partition p = bid&7 (blockIdx->XCD round-robin): counters cnt[p*256+b] and
// bucket data written ONLY by XCD p -> no cross-XCD line migration (the
// R8..R19 scatter killer: >=100k-line frontier -> 200MB HBM writes). Frontier
// here = 256 lines/XCD; appends share lines -> write-amp ~1 (12.8MB packed).
__global__ void bucket_fill_kernel(const int* __restrict__ src, const int* __restrict__ dst,
                                   int* __restrict__ cnt, int* __restrict__ bkt) {
    const int p = blockIdx.x & 7;
    int i = blockIdx.x * 256 + threadIdx.x;          // exact: 3125*256 = 800k quads
    int4 s4 = ((const int4*)src)[i];
    int4 d4 = ((const int4*)dst)[i];
    unsigned b, dl; int pos;
    b = (unsigned)d4.x / NPBK; dl = (unsigned)d4.x - b * NPBK;
    pos = atomicAdd(&cnt[(p << 8) + b], 1);
    if (pos < BCAP2) bkt[((size_t)((p << 8) + b) << 11) + pos] = (int)((dl << 17) | (unsigned)s4.x);
    b = (unsigned)d4.y / NPBK; dl = (unsigned)d4.y - b * NPBK;
    pos = atomicAdd(&cnt[(p << 8) + b], 1);
    if (pos < BCAP2) bkt[((size_t)((p << 8) + b) << 11) + pos] = (int)((dl << 17) | (unsigned)s4.y);
    b = (unsigned)d4.z / NPBK; dl = (unsigned)d4.z - b * NPBK;
    pos = atomicAdd(&cnt[(p << 8) + b], 1);
    if (pos < BCAP2) bkt[((size_t)((p << 8) + b) << 11) + pos] = (int)((dl << 17) | (unsigned)s4.z);
    b = (unsigned)d4.w / NPBK; dl = (unsigned)d4.w - b * NPBK;
    pos = atomicAdd(&cnt[(p << 8) + b], 1);
    if (pos < BCAP2) bkt[((size_t)((p << 8) + b) << 11) + pos] = (int)((dl << 17) | (unsigned)s4.w);
}

// ---------------- layer 1: t1 = xb @ W1 (R13-verbatim, standalone) ----------
__global__ __launch_bounds__(256) void gemm1_kernel(const short* __restrict__ xb,
                                                    const short* __restrict__ w1f,
                                                    float* __restrict__ t1) {
    __shared__ float red[4][256];
    const int tid = threadIdx.x;
    const int s = tid >> 6;                // wave / K-slice
    const int l = tid & 63;                // lane
    const int R0 = blockIdx.x * 16;
    const int g = l >> 4;                  // k-group
    const int c = l & 15;                  // A row / B col
    const int row = R0 + c;
    const size_t base = (size_t)row * XB_STRIDE + g * 8;
    const short* __restrict__ wfp = w1f + ((size_t)(s * NWIN) * 64 + l) * 8;

    short8v bf[NWIN];
#pragma unroll
    for (int wl = 0; wl < NWIN; ++wl)
        bf[wl] = *(const short8v*)(wfp + (size_t)wl * 512);

    short8v af[NWIN];
#pragma unroll
    for (int wl = 0; wl < NWIN; ++wl) {
        size_t off = base + (size_t)(s * NWIN + wl) * 32;
        if (off > XB_TOTAL - 8) off = XB_TOTAL - 8;   // last-row k>=1440 tail
        af[wl] = *(const short8v*)(xb + off);
    }

    float4v acc = {0.f, 0.f, 0.f, 0.f};
#pragma unroll
    for (int wl = 0; wl < NWIN; ++wl)
        acc = __builtin_amdgcn_mfma_f32_16x16x32_bf16(af[wl], bf[wl], acc, 0, 0, 0);

    // cross-wave K reduction (D map: col=l&15, row=4*(l>>4)+j — verified R6+)
#pragma unroll
    for (int j = 0; j < 4; ++j) red[s][l * 4 + j] = acc[j];
    __syncthreads();
    {
        int r = tid >> 4, cc = tid & 15;
        int idx = ((r >> 2) * 16 + cc) * 4 + (r & 3);
        float vv = red[0][idx] + red[1][idx] + red[2][idx] + red[3][idx];
        t1[(long)(R0 + r) * HID + cc] = vv;
    }
}

// ---------------- agg1: per-bucket LDS reduction over 8 partitions ----------
// Block b: zero hl[391][16] (25KB LDS), stream the 8 XCD-partitions' edges of
// bucket b (16 lanes/edge: t1[src] gather = one 64B L3-hot line, ds_add into
// hl[dstloc][f]), then h = relu(hl + t1 + b1). No global scatter anywhere.
__global__ __launch_bounds__(256) void agg1_kernel(const float* __restrict__ t1,
                                                   const int* __restrict__ cnt,
                                                   const int* __restrict__ bkt,
                                                   const float* __restrict__ b1,
                                                   float* __restrict__ h) {
    __shared__ float hl[NPBK][16];
    const int b = blockIdx.x;
    const int t = threadIdx.x;
    for (int idx = t; idx < NPBK * 16; idx += 256) ((float*)hl)[idx] = 0.f;
    __syncthreads();
    const int base = b * NPBK;
    const int eslot = t >> 4, f = t & 15;
    for (int p = 0; p < 8; ++p) {
        int ne = cnt[(p << 8) + b]; if (ne > BCAP2) ne = BCAP2;
        const int* __restrict__ bp = bkt + ((size_t)((p << 8) + b) << 11);
        for (int e = eslot; e < ne; e += 16) {
            int v = bp[e];
            int sn = v & SRCM;
            int dl = v >> 17;
            atomicAdd(&hl[dl][f], t1[(size_t)sn * 16 + f]);
        }
    }
    __syncthreads();
    for (int idx = t; idx < NPBK * 16; idx += 256) {
        int ln = idx >> 4, ff = idx & 15;
        int node = base + ln;
        if (node < N_NODES) {
            float vv = hl[ln][ff] + t1[(size_t)node * 16 + ff] + b1[ff];
            h[(size_t)node * 16 + ff] = fmaxf(vv, 0.f);
        }
    }
}

// ---------------- layer 2 (t2 padded to stride 8) ----------------
__global__ void gemm2_kernel(const float* __restrict__ h, const float* __restrict__ W2,
                             float* __restrict__ t2p) {
    int node = blockIdx.x * blockDim.x + threadIdx.x;
    if (node >= N_NODES) return;
    const float4* hr = (const float4*)(h + (size_t)node * HID);
    float hv[HID];
    ((float4*)hv)[0] = hr[0];
    ((float4*)hv)[1] = hr[1];
    ((float4*)hv)[2] = hr[2];
    ((float4*)hv)[3] = hr[3];
    float o8[8];
#pragma unroll
    for (int cNum = 0; cNum < N_CLS; ++cNum) {
        float a = 0.f;
#pragma unroll
        for (int j = 0; j < HID; ++j) a = fmaf(hv[j], W2[j * N_CLS + cNum], a);
        o8[cNum] = a;
    }
    o8[7] = 0.f;
    float4* op = (float4*)(t2p + (size_t)node * 8);
    op[0] = ((float4*)o8)[0];
    op[1] = ((float4*)o8)[1];
}

// ---------------- agg2: per-bucket LDS reduction (8 lanes/edge) -------------
__global__ __launch_bounds__(256) void agg2_kernel(const float* __restrict__ t2p,
                                                   const int* __restrict__ cnt,
                                                   const int* __restrict__ bkt,
                                                   const float* __restrict__ b2,
                                                   float* __restrict__ out) {
    __shared__ float ol[NPBK][8];
    const int b = blockIdx.x;
    const int t = threadIdx.x;
    for (int idx = t; idx < NPBK * 8; idx += 256) ((float*)ol)[idx] = 0.f;
    __syncthreads();
    const int base = b * NPBK;
    const int eslot = t >> 3, f = t & 7;
    for (int p = 0; p < 8; ++p) {
        int ne = cnt[(p << 8) + b]; if (ne > BCAP2) ne = BCAP2;
        const int* __restrict__ bp = bkt + ((size_t)((p << 8) + b) << 11);
        for (int e = eslot; e < ne; e += 32) {
            int v = bp[e];
            int sn = v & SRCM;
            int dl = v >> 17;
            atomicAdd(&ol[dl][f], t2p[(size_t)sn * 8 + f]);   // f==7 adds pad 0
        }
    }
    __syncthreads();
    for (int idx = t; idx < NPBK * 7; idx += 256) {
        int ln = idx / 7, c = idx - ln * 7;
        int node = base + ln;
        if (node < N_NODES)
            out[(size_t)node * 7 + c] = ol[ln][c] + t2p[(size_t)node * 8 + c] + b2[c];
    }
}

// ---------------- launch ----------------

extern "C" void kernel_launch(void* const* d_in, const int* in_sizes, int n_in,
                              void* d_out, int out_size, void* d_ws, size_t ws_size,
                              hipStream_t stream) {
    const float* x  = (const float*)d_in[0];
    const int*   ei = (const int*)d_in[1];
    const float* W1 = (const float*)d_in[2];
    const float* b1 = (const float*)d_in[3];
    const float* W2 = (const float*)d_in[4];
    const float* b2 = (const float*)d_in[5];
    const int* src = ei;
    const int* dst = ei + N_EDGES;
    float* out = (float*)d_out;

    char* w = (char*)d_ws;
    float* t1  = (float*)w;  w += (size_t)N_NODES * HID * sizeof(float);
    float* h   = (float*)w;  w += (size_t)N_NODES * HID * sizeof(float);
    float* t2p = (float*)w;  w += (size_t)N_NODES * 8 * sizeof(float);
    short* w1f = (short*)w;  w += (size_t)NWINT * 64 * 8 * sizeof(short);
    int* cnt   = (int*)w;    w += (size_t)8 * NBKT * sizeof(int);
    int* bkt   = (int*)w;    w += (size_t)8 * NBKT * BCAP2 * sizeof(int);
    short* xb  = (short*)w;  w += XB_TOTAL * sizeof(short) + 256;  // +slack

    hipMemsetAsync(cnt, 0, (size_t)8 * NBKT * sizeof(int), stream);
    prep_w1_kernel<<<NWINT, 64, 0, stream>>>(W1, w1f);
    repack_kernel<<<PBR, 256, 0, stream>>>(x, xb);
    bucket_fill_kernel<<<QBLK, 256, 0, stream>>>(src, dst, cnt, bkt);
    gemm1_kernel<<<GB1, 256, 0, stream>>>(xb, w1f, t1);
    agg1_kernel<<<NBKT, 256, 0, stream>>>(t1, cnt, bkt, b1, h);
    gemm2_kernel<<<ROWBLKS, 256, 0, stream>>>(h, W2, t2p);
    agg2_kernel<<<NBKT, 256, 0, stream>>>(t2p, cnt, bkt, b2, out);
}

// Round 21
// 668.340 us; speedup vs baseline: 1.8138x; 1.8138x over previous
//
#include <hip/hip_runtime.h>

#define N_NODES 100000
#define N_EDGES 3200000
#define F_IN    1433
#define HID     16
#define N_CLS   7
#define NWINT   48                                   // K windows of 32 (K padded to 1536)
#define NWIN    12                                   // windows per wave (4 waves)
#define GB1     (N_NODES / 16)                       // 6250 gemm tiles
#define QBLK    (N_EDGES / 4 / 256)                  // 3125 fill blocks (exact quads)
#define NTOT    (N_NODES * F_IN)                     // 143,300,000 (< 2^31)
#define NBKT    1024                                 // buckets
#define NPBK    98                                   // nodes per bucket (1024*98=100352)
#define BCAP2   512                                  // cap per (xcd,bucket); mean 391 +6σ
#define SRCM    0x1FFFF                              // 17-bit src mask

typedef __attribute__((ext_vector_type(8))) short short8v;
typedef __attribute__((ext_vector_type(4))) float float4v;

__device__ __forceinline__ unsigned short f2bf(float f) {
    unsigned u = __float_as_uint(f);
    u += 0x7fffu + ((u >> 16) & 1u);                 // RNE
    return (unsigned short)(u >> 16);
}

// ---------------- prep: pre-swizzled bf16 W1 fragments (zero past F_IN) -----
__global__ void prep_w1_kernel(const float* __restrict__ W1, short* __restrict__ w1f) {
    int w = blockIdx.x;
    int l = threadIdx.x;
    int col = l & 15;
    int kb = w * 32 + (l >> 4) * 8;
    short8v f;
#pragma unroll
    for (int i = 0; i < 8; ++i) {
        int k = kb + i;
        float v = (k < F_IN) ? W1[k * HID + col] : 0.f;
        f[i] = (short)f2bf(v);
    }
    *(short8v*)(w1f + ((size_t)w * 64 + l) * 8) = f;
}

// ---------------- fat1: gemm1 direct-from-x (first) ++ bucket fill (tail) ---
// Gemm arm: R16-verbatim (merge-proven VGPR~120): ALL 96 x-loads straight-line
// into registers, coalesced (instr covers rows {2j,2j+1} x 32 cols = 2 dense
// 128B lines); per-window wave-private LDS redistribute + MFMA. Over-reads
// past row end hit zero B-frags (w1f zero-padded). launch_bounds essential.
// Fill arm: XCD-private 8x1024 buckets (p=bid&7; R20-proven write-amp ~1,
// ~17MB total) -> tail hides under the BW-bound gemm, unlike ELL's 200MB.
__global__ __launch_bounds__(256) void fat1_kernel(const float* __restrict__ x,
                                                   const short* __restrict__ w1f,
                                                   float* __restrict__ t1,
                                                   const int* __restrict__ src,
                                                   const int* __restrict__ dst,
                                                   int* __restrict__ cnt,
                                                   int* __restrict__ bkt) {
    const int bid = blockIdx.x;
    if (bid >= GB1) {
        // ---- bucket fill path ----
        const int p = bid & 7;                       // blockIdx->XCD round-robin
        int i = (bid - GB1) * 256 + threadIdx.x;     // exact: 3125*256 = 800k quads
        int4 s4 = ((const int4*)src)[i];
        int4 d4 = ((const int4*)dst)[i];
        unsigned b, dl; int pos;
        b = (unsigned)d4.x / NPBK; dl = (unsigned)d4.x - b * NPBK;
        pos = atomicAdd(&cnt[(p << 10) + b], 1);
        if (pos < BCAP2) bkt[((size_t)((p << 10) + b) << 9) + pos] = (int)((dl << 17) | (unsigned)s4.x);
        b = (unsigned)d4.y / NPBK; dl = (unsigned)d4.y - b * NPBK;
        pos = atomicAdd(&cnt[(p << 10) + b], 1);
        if (pos < BCAP2) bkt[((size_t)((p << 10) + b) << 9) + pos] = (int)((dl << 17) | (unsigned)s4.y);
        b = (unsigned)d4.z / NPBK; dl = (unsigned)d4.z - b * NPBK;
        pos = atomicAdd(&cnt[(p << 10) + b], 1);
        if (pos < BCAP2) bkt[((size_t)((p << 10) + b) << 9) + pos] = (int)((dl << 17) | (unsigned)s4.z);
        b = (unsigned)d4.w / NPBK; dl = (unsigned)d4.w - b * NPBK;
        pos = atomicAdd(&cnt[(p << 10) + b], 1);
        if (pos < BCAP2) bkt[((size_t)((p << 10) + b) << 9) + pos] = (int)((dl << 17) | (unsigned)s4.w);
        return;
    }
    // ---- gemm1 path ----
    __shared__ short xs[4][16][40];        // per-wave staging, 80B row stride
    __shared__ float red[4][256];
    const int tid = threadIdx.x;
    const int s = tid >> 6;                // wave / K-slice
    const int l = tid & 63;                // lane
    const int R0 = bid * 16;
    const int g = l >> 4;                  // k-group
    const int c = l & 15;                  // A row / B col
    const int half = l >> 5;               // loader: row parity
    const int col = l & 31;                // loader: col within window
    const short* __restrict__ wfp = w1f + ((size_t)(s * NWIN) * 64 + l) * 8;

    float v[NWIN][8];
    if (bid != GB1 - 1) {                  // fast arm: unguarded
#pragma unroll
        for (int wl = 0; wl < NWIN; ++wl) {
            int kw = (s * NWIN + wl) * 32;
#pragma unroll
            for (int j = 0; j < 8; ++j)
                v[wl][j] = x[(size_t)((R0 + 2 * j + half) * F_IN + kw + col)];
        }
    } else {                               // final tile: clamp flat index
#pragma unroll
        for (int wl = 0; wl < NWIN; ++wl) {
            int kw = (s * NWIN + wl) * 32;
#pragma unroll
            for (int j = 0; j < 8; ++j) {
                int gi = (R0 + 2 * j + half) * F_IN + kw + col;
                if (gi > NTOT - 1) gi = NTOT - 1;
                v[wl][j] = x[gi];
            }
        }
    }

    float4v acc = {0.f, 0.f, 0.f, 0.f};
#pragma unroll
    for (int wl = 0; wl < NWIN; ++wl) {
#pragma unroll
        for (int j = 0; j < 8; ++j)
            xs[s][2 * j + half][col] = (short)f2bf(v[wl][j]);
        short8v af = *(const short8v*)&xs[s][c][g * 8];
        short8v bfv = *(const short8v*)(wfp + (size_t)wl * 512);
        acc = __builtin_amdgcn_mfma_f32_16x16x32_bf16(af, bfv, acc, 0, 0, 0);
    }

    // cross-wave K reduction (D map: col=l&15, row=4*(l>>4)+j — verified R6+)
#pragma unroll
    for (int j = 0; j < 4; ++j) red[s][l * 4 + j] = acc[j];
    __syncthreads();
    {
        int r = tid >> 4, cc = tid & 15;
        int idx = ((r >> 2) * 16 + cc) * 4 + (r & 3);
        float vv = red[0][idx] + red[1][idx] + red[2][idx] + red[3][idx];
        t1[(long)(R0 + r) * HID + cc] = vv;
    }
}

// ---------------- agg1 + fused gemm2: buckets -> h (LDS) -> t2p -------------
// Block b: zero hl[98][16], stream 8 XCD-partitions' edges (16 lanes/edge,
// UNROLL-4 -> 64 edges in flight; t1 gathers are hot-L2/L3 64B lines), then
// h = relu(hl + t1 + b1) in LDS, then t2p = h @ W2 (fused: h never touches
// global). 1024 blocks -> 4 blocks/CU (R20's 256-block grid was the 11%-occ
// latency wall).
__global__ __launch_bounds__(256) void agg1f_kernel(const float* __restrict__ t1,
                                                    const int* __restrict__ cnt,
                                                    const int* __restrict__ bkt,
                                                    const float* __restrict__ b1,
                                                    const float* __restrict__ W2,
                                                    float* __restrict__ t2p) {
    __shared__ float hl[NPBK][16];
    const int b = blockIdx.x;
    const int t = threadIdx.x;
    for (int idx = t; idx < NPBK * 16; idx += 256) ((float*)hl)[idx] = 0.f;
    __syncthreads();
    const int base = b * NPBK;
    const int eslot = t >> 4, f = t & 15;
    for (int p = 0; p < 8; ++p) {
        int ne = cnt[(p << 10) + b]; if (ne > BCAP2) ne = BCAP2;
        const int* __restrict__ bp = bkt + ((size_t)((p << 10) + b) << 9);
        int e = eslot;
        for (; e + 48 < ne; e += 64) {                // unroll-4: 64 edges in flight
            int v0 = bp[e], v1 = bp[e + 16], v2 = bp[e + 32], v3 = bp[e + 48];
            float x0 = t1[(size_t)(v0 & SRCM) * 16 + f];
            float x1 = t1[(size_t)(v1 & SRCM) * 16 + f];
            float x2 = t1[(size_t)(v2 & SRCM) * 16 + f];
            float x3 = t1[(size_t)(v3 & SRCM) * 16 + f];
            atomicAdd(&hl[v0 >> 17][f], x0);
            atomicAdd(&hl[v1 >> 17][f], x1);
            atomicAdd(&hl[v2 >> 17][f], x2);
            atomicAdd(&hl[v3 >> 17][f], x3);
        }
        for (; e < ne; e += 16) {
            int v = bp[e];
            atomicAdd(&hl[v >> 17][f], t1[(size_t)(v & SRCM) * 16 + f]);
        }
    }
    __syncthreads();
    // h = relu(hl + t1_self + b1), in place (coalesced t1 reads)
    for (int idx = t; idx < NPBK * 16; idx += 256) {
        int ln = idx >> 4, ff = idx & 15;
        int node = base + ln;
        if (node < N_NODES)
            hl[ln][ff] = fmaxf(hl[ln][ff] + t1[(size_t)node * 16 + ff] + b1[ff], 0.f);
    }
    __syncthreads();
    // fused gemm2: t2p[node*8+c] = sum_j h[j] * W2[j*7+c]  (c==7 -> pad 0)
    for (int idx = t; idx < NPBK * 8; idx += 256) {
        int ln = idx >> 3, c = idx & 7;
        int node = base + ln;
        if (node < N_NODES) {
            float a = 0.f;
            if (c < N_CLS) {
#pragma unroll
                for (int j = 0; j < HID; ++j) a = fmaf(hl[ln][j], W2[j * N_CLS + c], a);
            }
            t2p[(size_t)node * 8 + c] = a;
        }
    }
}

// ---------------- agg2: buckets -> out (8 lanes/edge, unroll-4) -------------
__global__ __launch_bounds__(256) void agg2_kernel(const float* __restrict__ t2p,
                                                   const int* __restrict__ cnt,
                                                   const int* __restrict__ bkt,
                                                   const float* __restrict__ b2,
                                                   float* __restrict__ out) {
    __shared__ float ol[NPBK][8];
    const int b = blockIdx.x;
    const int t = threadIdx.x;
    for (int idx = t; idx < NPBK * 8; idx += 256) ((float*)ol)[idx] = 0.f;
    __syncthreads();
    const int base = b * NPBK;
    const int eslot = t >> 3, f = t & 7;
    for (int p = 0; p < 8; ++p) {
        int ne = cnt[(p << 10) + b]; if (ne > BCAP2) ne = BCAP2;
        const int* __restrict__ bp = bkt + ((size_t)((p << 10) + b) << 9);
        int e = eslot;
        for (; e + 96 < ne; e += 128) {               // unroll-4: 128 edges in flight
            int v0 = bp[e], v1 = bp[e + 32], v2 = bp[e + 64], v3 = bp[e + 96];
            float x0 = t2p[(size_t)(v0 & SRCM) * 8 + f];   // f==7 reads pad 0
            float x1 = t2p[(size_t)(v1 & SRCM) * 8 + f];
            float x2 = t2p[(size_t)(v2 & SRCM) * 8 + f];
            float x3 = t2p[(size_t)(v3 & SRCM) * 8 + f];
            atomicAdd(&ol[v0 >> 17][f], x0);
            atomicAdd(&ol[v1 >> 17][f], x1);
            atomicAdd(&ol[v2 >> 17][f], x2);
            atomicAdd(&ol[v3 >> 17][f], x3);
        }
        for (; e < ne; e += 32) {
            int v = bp[e];
            atomicAdd(&ol[v >> 17][f], t2p[(size_t)(v & SRCM) * 8 + f]);
        }
    }
    __syncthreads();
    for (int idx = t; idx < NPBK * 7; idx += 256) {
        int ln = idx / 7, c = idx - ln * 7;
        int node = base + ln;
        if (node < N_NODES)
            out[(size_t)node * 7 + c] = ol[ln][c] + t2p[(size_t)node * 8 + c] + b2[c];
    }
}

// ---------------- launch ----------------

extern "C" void kernel_launch(void* const* d_in, const int* in_sizes, int n_in,
                              void* d_out, int out_size, void* d_ws, size_t ws_size,
                              hipStream_t stream) {
    const float* x  = (const float*)d_in[0];
    const int*   ei = (const int*)d_in[1];
    const float* W1 = (const float*)d_in[2];
    const float* b1 = (const float*)d_in[3];
    const float* W2 = (const float*)d_in[4];
    const float* b2 = (const float*)d_in[5];
    const int* src = ei;
    const int* dst = ei + N_EDGES;
    float* out = (float*)d_out;

    char* w = (char*)d_ws;
    float* t1  = (float*)w;  w += (size_t)N_NODES * HID * sizeof(float);
    float* t2p = (float*)w;  w += (size_t)N_NODES * 8 * sizeof(float);
    short* w1f = (short*)w;  w += (size_t)NWINT * 64 * 8 * sizeof(short);
    int* cnt   = (int*)w;    w += (size_t)8 * NBKT * sizeof(int);
    int* bkt   = (int*)w;    w += (size_t)8 * NBKT * BCAP2 * sizeof(int);

    hipMemsetAsync(cnt, 0, (size_t)8 * NBKT * sizeof(int), stream);
    prep_w1_kernel<<<NWINT, 64, 0, stream>>>(W1, w1f);

    // gemm1 direct-from-x (first) ++ XCD-private bucket fill (tail-hidden)
    fat1_kernel<<<GB1 + QBLK, 256, 0, stream>>>(x, w1f, t1, src, dst, cnt, bkt);

    agg1f_kernel<<<NBKT, 256, 0, stream>>>(t1, cnt, bkt, b1, W2, t2p);
    agg2_kernel<<<NBKT, 256, 0, stream>>>(t2p, cnt, bkt, b2, out);
}

// Round 22
// 465.899 us; speedup vs baseline: 2.6019x; 1.4345x over previous
//
#include <hip/hip_runtime.h>

#define N_NODES 100000
#define N_EDGES 3200000
#define F_IN    1433
#define HID     16
#define N_CLS   7
#define NWINT   48                                   // K windows of 32 (K padded to 1536)
#define NWIN    12                                   // windows per wave (4 waves)
#define GB1     (N_NODES / 16)                       // 6250 gemm tiles
#define XB_STRIDE 1440                               // padded bf16 row (2880B, 16B-aligned)
#define XB_TOTAL  ((size_t)N_NODES * XB_STRIDE)
#define NF4     (N_NODES * F_IN / 4)                 // 35,825,000 float4s (exact)
#define RPB     1536                                 // repack blocks (6/CU -> slots left for fill)
#define QBLK    (N_EDGES / 4 / 256)                  // 3125 fill blocks (exact quads)
#define NBKT    1024                                 // buckets
#define NPBK    98                                   // nodes per bucket (1024*98=100352)
#define BCAP2   512                                  // cap per (xcd,bucket); mean 391 +6σ
#define SRCM    0x1FFFF                              // 17-bit src mask

typedef __attribute__((ext_vector_type(8))) short short8v;
typedef __attribute__((ext_vector_type(4))) float float4v;

__device__ __forceinline__ unsigned short f2bf(float f) {
    unsigned u = __float_as_uint(f);
    u += 0x7fffu + ((u >> 16) & 1u);                 // RNE
    return (unsigned short)(u >> 16);
}

// ---------------- prep: pre-swizzled bf16 W1 fragments (zero past F_IN) -----
__global__ void prep_w1_kernel(const float* __restrict__ W1, short* __restrict__ w1f) {
    int w = blockIdx.x;
    int l = threadIdx.x;
    int col = l & 15;
    int kb = w * 32 + (l >> 4) * 8;
    short8v f;
#pragma unroll
    for (int i = 0; i < 8; ++i) {
        int k = kb + i;
        float v = (k < F_IN) ? W1[k * HID + col] : 0.f;
        f[i] = (short)f2bf(v);
    }
    *(short8v*)(w1f + ((size_t)w * 64 + l) * 8) = f;
}

// ---------------- fatprep: repack (1536 blocks) ++ bucket fill (slot-shared)
// Repack capped at 6 blocks/CU -> fill blocks become RESIDENT immediately and
// run in repack's memory-stall slots (R13's 2048-block repack monopolized all
// slots -> serial fill). Fill = XCD-private 8x1024 buckets (p=bid&7): no
// cross-XCD counter/line migration (R20-proven), ~17MB writes (vs ELL 200MB)
// so no R14-style BW thrash.
__global__ __launch_bounds__(256) void fatprep_kernel(const float* __restrict__ x,
                                                      short* __restrict__ xb,
                                                      const int* __restrict__ src,
                                                      const int* __restrict__ dst,
                                                      int* __restrict__ cnt,
                                                      int* __restrict__ bkt) {
    const int bid = blockIdx.x;
    if (bid < RPB) {
        // ---- repack path (grid-stride) ----
        for (long i4 = (long)bid * 256 + threadIdx.x; i4 < NF4; i4 += (long)RPB * 256) {
            float4 v = ((const float4*)x)[i4];
            float fv[4] = {v.x, v.y, v.z, v.w};
            unsigned e0 = (unsigned)(i4 * 4);
#pragma unroll
            for (int j = 0; j < 4; ++j) {
                unsigned e = e0 + j;
                unsigned row = e / 1433u;             // magic-mul
                unsigned col = e - row * 1433u;
                xb[(size_t)row * XB_STRIDE + col] = (short)f2bf(fv[j]);
            }
        }
        for (int p = bid * 256 + threadIdx.x; p < N_NODES * 7; p += RPB * 256) {
            int row = p / 7;
            int col = 1433 + (p - row * 7);
            xb[(size_t)row * XB_STRIDE + col] = 0;
        }
        return;
    }
    // ---- bucket fill path ----
    const int p = bid & 7;                           // blockIdx->XCD round-robin
    int i = (bid - RPB) * 256 + threadIdx.x;         // exact: 3125*256 = 800k quads
    int4 s4 = ((const int4*)src)[i];
    int4 d4 = ((const int4*)dst)[i];
    unsigned b, dl; int pos;
    b = (unsigned)d4.x / NPBK; dl = (unsigned)d4.x - b * NPBK;
    pos = atomicAdd(&cnt[(p << 10) + b], 1);
    if (pos < BCAP2) bkt[((size_t)((p << 10) + b) << 9) + pos] = (int)((dl << 17) | (unsigned)s4.x);
    b = (unsigned)d4.y / NPBK; dl = (unsigned)d4.y - b * NPBK;
    pos = atomicAdd(&cnt[(p << 10) + b], 1);
    if (pos < BCAP2) bkt[((size_t)((p << 10) + b) << 9) + pos] = (int)((dl << 17) | (unsigned)s4.y);
    b = (unsigned)d4.z / NPBK; dl = (unsigned)d4.z - b * NPBK;
    pos = atomicAdd(&cnt[(p << 10) + b], 1);
    if (pos < BCAP2) bkt[((size_t)((p << 10) + b) << 9) + pos] = (int)((dl << 17) | (unsigned)s4.z);
    b = (unsigned)d4.w / NPBK; dl = (unsigned)d4.w - b * NPBK;
    pos = atomicAdd(&cnt[(p << 10) + b], 1);
    if (pos < BCAP2) bkt[((size_t)((p << 10) + b) << 9) + pos] = (int)((dl << 17) | (unsigned)s4.w);
}

// ---------------- layer 1: t1 = xb @ W1 (R13-verbatim, measured ~95us) ------
__global__ __launch_bounds__(256) void gemm1_kernel(const short* __restrict__ xb,
                                                    const short* __restrict__ w1f,
                                                    float* __restrict__ t1) {
    __shared__ float red[4][256];
    const int tid = threadIdx.x;
    const int s = tid >> 6;                // wave / K-slice
    const int l = tid & 63;                // lane
    const int R0 = blockIdx.x * 16;
    const int g = l >> 4;                  // k-group
    const int c = l & 15;                  // A row / B col
    const int row = R0 + c;
    const size_t base = (size_t)row * XB_STRIDE + g * 8;
    const short* __restrict__ wfp = w1f + ((size_t)(s * NWIN) * 64 + l) * 8;

    short8v bf[NWIN];
#pragma unroll
    for (int wl = 0; wl < NWIN; ++wl)
        bf[wl] = *(const short8v*)(wfp + (size_t)wl * 512);

    short8v af[NWIN];
#pragma unroll
    for (int wl = 0; wl < NWIN; ++wl) {
        size_t off = base + (size_t)(s * NWIN + wl) * 32;
        if (off > XB_TOTAL - 8) off = XB_TOTAL - 8;   // last-row k>=1440 tail
        af[wl] = *(const short8v*)(xb + off);
    }

    float4v acc = {0.f, 0.f, 0.f, 0.f};
#pragma unroll
    for (int wl = 0; wl < NWIN; ++wl)
        acc = __builtin_amdgcn_mfma_f32_16x16x32_bf16(af[wl], bf[wl], acc, 0, 0, 0);

    // cross-wave K reduction (D map: col=l&15, row=4*(l>>4)+j — verified R6+)
#pragma unroll
    for (int j = 0; j < 4; ++j) red[s][l * 4 + j] = acc[j];
    __syncthreads();
    {
        int r = tid >> 4, cc = tid & 15;
        int idx = ((r >> 2) * 16 + cc) * 4 + (r & 3);
        float vv = red[0][idx] + red[1][idx] + red[2][idx] + red[3][idx];
        t1[(long)(R0 + r) * HID + cc] = vv;
    }
}

// ---------------- agg1 + fused gemm2: LDS-CSR node-centric ----------------
// Block b: stage its 8 partitions' edges into LDS (<=4096), build per-node
// CSR in LDS (count + Hillis-Steele scan + scatter, ~3k LDS ops), then
// R7/R16-style node-centric gathers (4 lanes/node x float4 = one 64B line
// per edge, massive TLP) -> h in LDS -> fused h @ W2 -> t2p. No global
// scatter; no global-LDS atomic storm (R20/R21's 300us agg killer).
__global__ __launch_bounds__(256) void agg1f_kernel(const float* __restrict__ t1,
                                                    const int* __restrict__ cnt,
                                                    const int* __restrict__ bkt,
                                                    const float* __restrict__ b1,
                                                    const float* __restrict__ W2,
                                                    float* __restrict__ t2p) {
    __shared__ int els[4096];
    __shared__ int ecsr[4096];
    __shared__ int dcnt[128], doff[128], dcur[128];
    __shared__ int pbase[9];
    __shared__ float hl[NPBK][16];
    const int b = blockIdx.x;
    const int t = threadIdx.x;
    if (t == 0) {
        int s = 0;
        for (int p = 0; p < 8; ++p) {
            pbase[p] = s;
            int ne = cnt[(p << 10) + b]; if (ne > BCAP2) ne = BCAP2;
            s += ne;
        }
        pbase[8] = s;
    }
    if (t < 128) dcnt[t] = 0;
    __syncthreads();
    const int nt = pbase[8];
    // stage
    for (int p = 0; p < 8; ++p) {
        int base0 = pbase[p], ne = pbase[p + 1] - base0;
        const int* __restrict__ bp = bkt + ((size_t)((p << 10) + b) << 9);
        for (int e = t; e < ne; e += 256) els[base0 + e] = bp[e];
    }
    __syncthreads();
    // count
    for (int e = t; e < nt; e += 256) atomicAdd(&dcnt[els[e] >> 17], 1);
    __syncthreads();
    // inclusive scan over 128 (Hillis-Steele, uniform barriers)
    if (t < 128) doff[t] = dcnt[t];
    __syncthreads();
    for (int d = 1; d < 128; d <<= 1) {
        int add = (t < 128 && t >= d) ? doff[t - d] : 0;
        __syncthreads();
        if (t < 128) doff[t] += add;
        __syncthreads();
    }
    if (t < 128) dcur[t] = doff[t] - dcnt[t];        // exclusive offsets
    __syncthreads();
    // scatter to LDS-CSR
    for (int e = t; e < nt; e += 256) {
        int v = els[e];
        int pos = atomicAdd(&dcur[v >> 17], 1);
        ecsr[pos] = v & SRCM;
    }
    __syncthreads();
    // node-centric: 4 lanes/node, float4 gathers
    const int nbase = b * NPBK;
    {
        int q = t & 3;
        for (int nl = t >> 2; nl < NPBK; nl += 64) {
            int node = nbase + nl;
            if (node < N_NODES) {
                int o = doff[nl] - dcnt[nl];
                int d = dcnt[nl];
                float4 a = *(const float4*)(t1 + ((size_t)node * 16 + q * 4));
                float4 bb = *(const float4*)(b1 + q * 4);
                a.x += bb.x; a.y += bb.y; a.z += bb.z; a.w += bb.w;
                for (int e = 0; e < d; ++e) {
                    int s = ecsr[o + e];
                    float4 v = *(const float4*)(t1 + ((size_t)s * 16 + q * 4));
                    a.x += v.x; a.y += v.y; a.z += v.z; a.w += v.w;
                }
                float4 r = {fmaxf(a.x, 0.f), fmaxf(a.y, 0.f),
                            fmaxf(a.z, 0.f), fmaxf(a.w, 0.f)};
                *(float4*)(&hl[nl][q * 4]) = r;
            }
        }
    }
    __syncthreads();
    // fused gemm2: t2p[node*8+c] = h . W2[:,c]
    for (int idx = t; idx < NPBK * 8; idx += 256) {
        int ln = idx >> 3, c = idx & 7;
        int node = nbase + ln;
        if (node < N_NODES) {
            float a = 0.f;
            if (c < N_CLS) {
#pragma unroll
                for (int j = 0; j < HID; ++j) a = fmaf(hl[ln][j], W2[j * N_CLS + c], a);
            }
            t2p[(size_t)node * 8 + c] = a;
        }
    }
}

// ---------------- agg2: LDS-CSR node-centric (2 lanes/node) ----------------
__global__ __launch_bounds__(256) void agg2_kernel(const float* __restrict__ t2p,
                                                   const int* __restrict__ cnt,
                                                   const int* __restrict__ bkt,
                                                   const float* __restrict__ b2,
                                                   float* __restrict__ out) {
    __shared__ int els[4096];
    __shared__ int ecsr[4096];
    __shared__ int dcnt[128], doff[128], dcur[128];
    __shared__ int pbase[9];
    const int b = blockIdx.x;
    const int t = threadIdx.x;
    if (t == 0) {
        int s = 0;
        for (int p = 0; p < 8; ++p) {
            pbase[p] = s;
            int ne = cnt[(p << 10) + b]; if (ne > BCAP2) ne = BCAP2;
            s += ne;
        }
        pbase[8] = s;
    }
    if (t < 128) dcnt[t] = 0;
    __syncthreads();
    const int nt = pbase[8];
    for (int p = 0; p < 8; ++p) {
        int base0 = pbase[p], ne = pbase[p + 1] - base0;
        const int* __restrict__ bp = bkt + ((size_t)((p << 10) + b) << 9);
        for (int e = t; e < ne; e += 256) els[base0 + e] = bp[e];
    }
    __syncthreads();
    for (int e = t; e < nt; e += 256) atomicAdd(&dcnt[els[e] >> 17], 1);
    __syncthreads();
    if (t < 128) doff[t] = dcnt[t];
    __syncthreads();
    for (int d = 1; d < 128; d <<= 1) {
        int add = (t < 128 && t >= d) ? doff[t - d] : 0;
        __syncthreads();
        if (t < 128) doff[t] += add;
        __syncthreads();
    }
    if (t < 128) dcur[t] = doff[t] - dcnt[t];
    __syncthreads();
    for (int e = t; e < nt; e += 256) {
        int v = els[e];
        int pos = atomicAdd(&dcur[v >> 17], 1);
        ecsr[pos] = v & SRCM;
    }
    __syncthreads();
    const int nbase = b * NPBK;
    {
        int q = t & 1;
        for (int nl = t >> 1; nl < NPBK; nl += 128) {
            int node = nbase + nl;
            if (node < N_NODES) {
                int o = doff[nl] - dcnt[nl];
                int d = dcnt[nl];
                float4 a = *(const float4*)(t2p + ((size_t)node * 8 + q * 4));
                if (q == 0) {
                    a.x += b2[0]; a.y += b2[1]; a.z += b2[2]; a.w += b2[3];
                } else {
                    a.x += b2[4]; a.y += b2[5]; a.z += b2[6];
                }
                for (int e = 0; e < d; ++e) {
                    int s = ecsr[o + e];
                    float4 v = *(const float4*)(t2p + ((size_t)s * 8 + q * 4));
                    a.x += v.x; a.y += v.y; a.z += v.z; a.w += v.w;
                }
                float* op = out + (size_t)node * 7 + q * 4;
                op[0] = a.x; op[1] = a.y; op[2] = a.z;
                if (q == 0) op[3] = a.w;
            }
        }
    }
}

// ---------------- launch ----------------

extern "C" void kernel_launch(void* const* d_in, const int* in_sizes, int n_in,
                              void* d_out, int out_size, void* d_ws, size_t ws_size,
                              hipStream_t stream) {
    const float* x  = (const float*)d_in[0];
    const int*   ei = (const int*)d_in[1];
    const float* W1 = (const float*)d_in[2];
    const float* b1 = (const float*)d_in[3];
    const float* W2 = (const float*)d_in[4];
    const float* b2 = (const float*)d_in[5];
    const int* src = ei;
    const int* dst = ei + N_EDGES;
    float* out = (float*)d_out;

    char* w = (char*)d_ws;
    float* t1  = (float*)w;  w += (size_t)N_NODES * HID * sizeof(float);
    float* t2p = (float*)w;  w += (size_t)N_NODES * 8 * sizeof(float);
    short* w1f = (short*)w;  w += (size_t)NWINT * 64 * 8 * sizeof(short);
    int* cnt   = (int*)w;    w += (size_t)8 * NBKT * sizeof(int);
    int* bkt   = (int*)w;    w += (size_t)8 * NBKT * BCAP2 * sizeof(int);
    short* xb  = (short*)w;  w += XB_TOTAL * sizeof(short) + 256;  // +slack

    hipMemsetAsync(cnt, 0, (size_t)8 * NBKT * sizeof(int), stream);
    prep_w1_kernel<<<NWINT, 64, 0, stream>>>(W1, w1f);

    // repack (capped grid, slots left) ++ bucket fill (co-resident)
    fatprep_kernel<<<RPB + QBLK, 256, 0, stream>>>(x, xb, src, dst, cnt, bkt);

    gemm1_kernel<<<GB1, 256, 0, stream>>>(xb, w1f, t1);
    agg1f_kernel<<<NBKT, 256, 0, stream>>>(t1, cnt, bkt, b1, W2, t2p);
    agg2_kernel<<<NBKT, 256, 0, stream>>>(t2p, cnt, bkt, b2, out);
}

// Round 23
// 357.616 us; speedup vs baseline: 3.3897x; 1.3028x over previous
//
#include <hip/hip_runtime.h>

#define N_NODES 100000
#define N_EDGES 3200000
#define F_IN    1433
#define HID     16
#define N_CLS   7
#define NWINT   48                                   // K windows of 32 (K padded to 1536)
#define NWIN    12                                   // windows per wave (4 waves)
#define GB1     (N_NODES / 16)                       // 6250 gemm tiles
#define QBLK    (N_EDGES / 4 / 256)                  // 3125 fill blocks (exact quads)
#define NTOT    ((long)N_NODES * F_IN)               // 143,300,000
#define NBKT    1024                                 // buckets
#define NPBK    98                                   // nodes per bucket (1024*98=100352)
#define BCAP2   512                                  // cap per (xcd,bucket); mean 391 +6σ
#define SRCM    0x1FFFF                              // 17-bit src mask

typedef __attribute__((ext_vector_type(8))) short short8v;
typedef __attribute__((ext_vector_type(4))) float float4v;
typedef float float4u __attribute__((ext_vector_type(4), aligned(4)));  // dword-aligned dwordx4

__device__ __forceinline__ unsigned short f2bf(float f) {
    unsigned u = __float_as_uint(f);
    u += 0x7fffu + ((u >> 16) & 1u);                 // RNE
    return (unsigned short)(u >> 16);
}

// ---------------- prep: pre-swizzled bf16 W1 fragments (zero past F_IN) -----
__global__ void prep_w1_kernel(const float* __restrict__ W1, short* __restrict__ w1f) {
    int w = blockIdx.x;
    int l = threadIdx.x;
    int col = l & 15;
    int kb = w * 32 + (l >> 4) * 8;
    short8v f;
#pragma unroll
    for (int i = 0; i < 8; ++i) {
        int k = kb + i;
        float v = (k < F_IN) ? W1[k * HID + col] : 0.f;
        f[i] = (short)f2bf(v);
    }
    *(short8v*)(w1f + ((size_t)w * 64 + l) * 8) = f;
}

// ---------------- bucket fill: XCD-private 8x1024 buckets (R20/R22-proven) --
__global__ void bucket_fill_kernel(const int* __restrict__ src, const int* __restrict__ dst,
                                   int* __restrict__ cnt, int* __restrict__ bkt) {
    const int p = blockIdx.x & 7;                    // blockIdx->XCD round-robin
    int i = blockIdx.x * 256 + threadIdx.x;          // exact: 3125*256 = 800k quads
    int4 s4 = ((const int4*)src)[i];
    int4 d4 = ((const int4*)dst)[i];
    unsigned b, dl; int pos;
    b = (unsigned)d4.x / NPBK; dl = (unsigned)d4.x - b * NPBK;
    pos = atomicAdd(&cnt[(p << 10) + b], 1);
    if (pos < BCAP2) bkt[((size_t)((p << 10) + b) << 9) + pos] = (int)((dl << 17) | (unsigned)s4.x);
    b = (unsigned)d4.y / NPBK; dl = (unsigned)d4.y - b * NPBK;
    pos = atomicAdd(&cnt[(p << 10) + b], 1);
    if (pos < BCAP2) bkt[((size_t)((p << 10) + b) << 9) + pos] = (int)((dl << 17) | (unsigned)s4.y);
    b = (unsigned)d4.z / NPBK; dl = (unsigned)d4.z - b * NPBK;
    pos = atomicAdd(&cnt[(p << 10) + b], 1);
    if (pos < BCAP2) bkt[((size_t)((p << 10) + b) << 9) + pos] = (int)((dl << 17) | (unsigned)s4.z);
    b = (unsigned)d4.w / NPBK; dl = (unsigned)d4.w - b * NPBK;
    pos = atomicAdd(&cnt[(p << 10) + b], 1);
    if (pos < BCAP2) bkt[((size_t)((p << 10) + b) << 9) + pos] = (int)((dl << 17) | (unsigned)s4.w);
}

// ---------------- layer 1: t1 = x @ W1 DIRECT from f32 x --------------------
// R13 structure (straight-line all-window register staging, VGPR~150,
// launch_bounds essential per R10) but NO repack: lane (g,c) loads its 8
// consecutive floats per window as TWO dword-aligned dwordx4 (float4u —
// CDNA multi-dword loads need only 4B alignment). Per window a wave covers
// 128B dense per row. f2bf at use time. Over-reads past row end hit zero
// B-frags (w1f zero-padded); only the final tile clamps the flat index.
__global__ __launch_bounds__(256) void gemm1_kernel(const float* __restrict__ x,
                                                    const short* __restrict__ w1f,
                                                    float* __restrict__ t1) {
    __shared__ float red[4][256];
    const int tid = threadIdx.x;
    const int s = tid >> 6;                // wave / K-slice
    const int l = tid & 63;                // lane
    const int R0 = blockIdx.x * 16;
    const int g = l >> 4;                  // k-group
    const int c = l & 15;                  // A row / B col
    const int row = R0 + c;
    const long base = (long)row * F_IN + g * 8;
    const short* __restrict__ wfp = w1f + ((size_t)(s * NWIN) * 64 + l) * 8;

    short8v bf[NWIN];
#pragma unroll
    for (int wl = 0; wl < NWIN; ++wl)
        bf[wl] = *(const short8v*)(wfp + (size_t)wl * 512);

    float4u va[NWIN][2];
    if (blockIdx.x != GB1 - 1) {           // fast arm: unguarded
#pragma unroll
        for (int wl = 0; wl < NWIN; ++wl) {
            long kb = base + (long)(s * NWIN + wl) * 32;
            va[wl][0] = *(const float4u*)(x + kb);
            va[wl][1] = *(const float4u*)(x + kb + 4);
        }
    } else {                               // final tile: clamp flat index
#pragma unroll
        for (int wl = 0; wl < NWIN; ++wl) {
            long kb = base + (long)(s * NWIN + wl) * 32;
            if (kb > NTOT - 8) kb = NTOT - 8;
            va[wl][0] = *(const float4u*)(x + kb);
            va[wl][1] = *(const float4u*)(x + kb + 4);
        }
    }

    float4v acc = {0.f, 0.f, 0.f, 0.f};
#pragma unroll
    for (int wl = 0; wl < NWIN; ++wl) {
        short8v af;
#pragma unroll
        for (int i = 0; i < 4; ++i) af[i] = (short)f2bf(va[wl][0][i]);
#pragma unroll
        for (int i = 0; i < 4; ++i) af[4 + i] = (short)f2bf(va[wl][1][i]);
        acc = __builtin_amdgcn_mfma_f32_16x16x32_bf16(af, bf[wl], acc, 0, 0, 0);
    }

    // cross-wave K reduction (D map: col=l&15, row=4*(l>>4)+j — verified R6+)
#pragma unroll
    for (int j = 0; j < 4; ++j) red[s][l * 4 + j] = acc[j];
    __syncthreads();
    {
        int r = tid >> 4, cc = tid & 15;
        int idx = ((r >> 2) * 16 + cc) * 4 + (r & 3);
        float vv = red[0][idx] + red[1][idx] + red[2][idx] + red[3][idx];
        t1[(long)(R0 + r) * HID + cc] = vv;
    }
}

// ---------------- agg1 + fused gemm2: LDS-CSR node-centric (R22-proven) -----
__global__ __launch_bounds__(256) void agg1f_kernel(const float* __restrict__ t1,
                                                    const int* __restrict__ cnt,
                                                    const int* __restrict__ bkt,
                                                    const float* __restrict__ b1,
                                                    const float* __restrict__ W2,
                                                    float* __restrict__ t2p) {
    __shared__ int els[4096];
    __shared__ int ecsr[4096];
    __shared__ int dcnt[128], doff[128], dcur[128];
    __shared__ int pbase[9];
    __shared__ float hl[NPBK][16];
    const int b = blockIdx.x;
    const int t = threadIdx.x;
    if (t == 0) {
        int s = 0;
        for (int p = 0; p < 8; ++p) {
            pbase[p] = s;
            int ne = cnt[(p << 10) + b]; if (ne > BCAP2) ne = BCAP2;
            s += ne;
        }
        pbase[8] = s;
    }
    if (t < 128) dcnt[t] = 0;
    __syncthreads();
    const int nt = pbase[8];
    for (int p = 0; p < 8; ++p) {
        int base0 = pbase[p], ne = pbase[p + 1] - base0;
        const int* __restrict__ bp = bkt + ((size_t)((p << 10) + b) << 9);
        for (int e = t; e < ne; e += 256) els[base0 + e] = bp[e];
    }
    __syncthreads();
    for (int e = t; e < nt; e += 256) atomicAdd(&dcnt[els[e] >> 17], 1);
    __syncthreads();
    if (t < 128) doff[t] = dcnt[t];
    __syncthreads();
    for (int d = 1; d < 128; d <<= 1) {
        int add = (t < 128 && t >= d) ? doff[t - d] : 0;
        __syncthreads();
        if (t < 128) doff[t] += add;
        __syncthreads();
    }
    if (t < 128) dcur[t] = doff[t] - dcnt[t];        // exclusive offsets
    __syncthreads();
    for (int e = t; e < nt; e += 256) {
        int v = els[e];
        int pos = atomicAdd(&dcur[v >> 17], 1);
        ecsr[pos] = v & SRCM;
    }
    __syncthreads();
    const int nbase = b * NPBK;
    {
        int q = t & 3;
        for (int nl = t >> 2; nl < NPBK; nl += 64) {
            int node = nbase + nl;
            if (node < N_NODES) {
                int o = doff[nl] - dcnt[nl];
                int d = dcnt[nl];
                float4 a = *(const float4*)(t1 + ((size_t)node * 16 + q * 4));
                float4 bb = *(const float4*)(b1 + q * 4);
                a.x += bb.x; a.y += bb.y; a.z += bb.z; a.w += bb.w;
                for (int e = 0; e < d; ++e) {
                    int s = ecsr[o + e];
                    float4 v = *(const float4*)(t1 + ((size_t)s * 16 + q * 4));
                    a.x += v.x; a.y += v.y; a.z += v.z; a.w += v.w;
                }
                float4 r = {fmaxf(a.x, 0.f), fmaxf(a.y, 0.f),
                            fmaxf(a.z, 0.f), fmaxf(a.w, 0.f)};
                *(float4*)(&hl[nl][q * 4]) = r;
            }
        }
    }
    __syncthreads();
    for (int idx = t; idx < NPBK * 8; idx += 256) {
        int ln = idx >> 3, c = idx & 7;
        int node = nbase + ln;
        if (node < N_NODES) {
            float a = 0.f;
            if (c < N_CLS) {
#pragma unroll
                for (int j = 0; j < HID; ++j) a = fmaf(hl[ln][j], W2[j * N_CLS + c], a);
            }
            t2p[(size_t)node * 8 + c] = a;
        }
    }
}

// ---------------- agg2: LDS-CSR node-centric (R22-proven) ----------------
__global__ __launch_bounds__(256) void agg2_kernel(const float* __restrict__ t2p,
                                                   const int* __restrict__ cnt,
                                                   const int* __restrict__ bkt,
                                                   const float* __restrict__ b2,
                                                   float* __restrict__ out) {
    __shared__ int els[4096];
    __shared__ int ecsr[4096];
    __shared__ int dcnt[128], doff[128], dcur[128];
    __shared__ int pbase[9];
    const int b = blockIdx.x;
    const int t = threadIdx.x;
    if (t == 0) {
        int s = 0;
        for (int p = 0; p < 8; ++p) {
            pbase[p] = s;
            int ne = cnt[(p << 10) + b]; if (ne > BCAP2) ne = BCAP2;
            s += ne;
        }
        pbase[8] = s;
    }
    if (t < 128) dcnt[t] = 0;
    __syncthreads();
    const int nt = pbase[8];
    for (int p = 0; p < 8; ++p) {
        int base0 = pbase[p], ne = pbase[p + 1] - base0;
        const int* __restrict__ bp = bkt + ((size_t)((p << 10) + b) << 9);
        for (int e = t; e < ne; e += 256) els[base0 + e] = bp[e];
    }
    __syncthreads();
    for (int e = t; e < nt; e += 256) atomicAdd(&dcnt[els[e] >> 17], 1);
    __syncthreads();
    if (t < 128) doff[t] = dcnt[t];
    __syncthreads();
    for (int d = 1; d < 128; d <<= 1) {
        int add = (t < 128 && t >= d) ? doff[t - d] : 0;
        __syncthreads();
        if (t < 128) doff[t] += add;
        __syncthreads();
    }
    if (t < 128) dcur[t] = doff[t] - dcnt[t];
    __syncthreads();
    for (int e = t; e < nt; e += 256) {
        int v = els[e];
        int pos = atomicAdd(&dcur[v >> 17], 1);
        ecsr[pos] = v & SRCM;
    }
    __syncthreads();
    const int nbase = b * NPBK;
    {
        int q = t & 1;
        for (int nl = t >> 1; nl < NPBK; nl += 128) {
            int node = nbase + nl;
            if (node < N_NODES) {
                int o = doff[nl] - dcnt[nl];
                int d = dcnt[nl];
                float4 a = *(const float4*)(t2p + ((size_t)node * 8 + q * 4));
                if (q == 0) {
                    a.x += b2[0]; a.y += b2[1]; a.z += b2[2]; a.w += b2[3];
                } else {
                    a.x += b2[4]; a.y += b2[5]; a.z += b2[6];
                }
                for (int e = 0; e < d; ++e) {
                    int s = ecsr[o + e];
                    float4 v = *(const float4*)(t2p + ((size_t)s * 8 + q * 4));
                    a.x += v.x; a.y += v.y; a.z += v.z; a.w += v.w;
                }
                float* op = out + (size_t)node * 7 + q * 4;
                op[0] = a.x; op[1] = a.y; op[2] = a.z;
                if (q == 0) op[3] = a.w;
            }
        }
    }
}

// ---------------- launch ----------------

extern "C" void kernel_launch(void* const* d_in, const int* in_sizes, int n_in,
                              void* d_out, int out_size, void* d_ws, size_t ws_size,
                              hipStream_t stream) {
    const float* x  = (const float*)d_in[0];
    const int*   ei = (const int*)d_in[1];
    const float* W1 = (const float*)d_in[2];
    const float* b1 = (const float*)d_in[3];
    const float* W2 = (const float*)d_in[4];
    const float* b2 = (const float*)d_in[5];
    const int* src = ei;
    const int* dst = ei + N_EDGES;
    float* out = (float*)d_out;

    char* w = (char*)d_ws;
    float* t1  = (float*)w;  w += (size_t)N_NODES * HID * sizeof(float);
    float* t2p = (float*)w;  w += (size_t)N_NODES * 8 * sizeof(float);
    short* w1f = (short*)w;  w += (size_t)NWINT * 64 * 8 * sizeof(short);
    int* cnt   = (int*)w;    w += (size_t)8 * NBKT * sizeof(int);
    int* bkt   = (int*)w;    w += (size_t)8 * NBKT * BCAP2 * sizeof(int);

    hipMemsetAsync(cnt, 0, (size_t)8 * NBKT * sizeof(int), stream);
    prep_w1_kernel<<<NWINT, 64, 0, stream>>>(W1, w1f);
    bucket_fill_kernel<<<QBLK, 256, 0, stream>>>(src, dst, cnt, bkt);
    gemm1_kernel<<<GB1, 256, 0, stream>>>(x, w1f, t1);
    agg1f_kernel<<<NBKT, 256, 0, stream>>>(t1, cnt, bkt, b1, W2, t2p);
    agg2_kernel<<<NBKT, 256, 0, stream>>>(t2p, cnt, bkt, b2, out);
}

// Round 24
// 343.570 us; speedup vs baseline: 3.5283x; 1.0409x over previous
//
#include <hip/hip_runtime.h>

#define N_NODES 100000
#define N_EDGES 3200000
#define F_IN    1433
#define HID     16
#define N_CLS   7
#define NWINT   48                                   // K windows of 32 (K padded to 1536)
#define NWIN    12                                   // windows per wave (4 waves)
#define GB1     (N_NODES / 16)                       // 6250 gemm tiles
#define QBLK    (N_EDGES / 4 / 256)                  // 3125 fill blocks (exact quads)
#define NTOT    ((long)N_NODES * F_IN)               // 143,300,000
#define NBKT    1024                                 // buckets
#define NPBK    98                                   // nodes per bucket (1024*98=100352)
#define BCAP2   512                                  // cap per (xcd,bucket); mean 391 +6σ
#define SRCM    0x1FFFF                              // 17-bit src mask

typedef __attribute__((ext_vector_type(8))) short short8v;
typedef __attribute__((ext_vector_type(4))) float float4v;
typedef float float4u __attribute__((ext_vector_type(4), aligned(4)));  // dword-aligned dwordx4

__device__ __forceinline__ unsigned short f2bf(float f) {
    unsigned u = __float_as_uint(f);
    u += 0x7fffu + ((u >> 16) & 1u);                 // RNE
    return (unsigned short)(u >> 16);
}

// ---------------- prep: pre-swizzled bf16 W1 fragments (zero past F_IN) -----
__global__ void prep_w1_kernel(const float* __restrict__ W1, short* __restrict__ w1f) {
    int w = blockIdx.x;
    int l = threadIdx.x;
    int col = l & 15;
    int kb = w * 32 + (l >> 4) * 8;
    short8v f;
#pragma unroll
    for (int i = 0; i < 8; ++i) {
        int k = kb + i;
        float v = (k < F_IN) ? W1[k * HID + col] : 0.f;
        f[i] = (short)f2bf(v);
    }
    *(short8v*)(w1f + ((size_t)w * 64 + l) * 8) = f;
}

// ---------------- gemm arm (noinline: isolated codegen, R19-collapse guard) -
__device__ __noinline__ void gemm_arm(int bid, const float* __restrict__ x,
                                      const short* __restrict__ w1f,
                                      float* __restrict__ t1) {
    __shared__ float red[4][256];
    const int tid = threadIdx.x;
    const int s = tid >> 6;                // wave / K-slice
    const int l = tid & 63;                // lane
    const int R0 = bid * 16;
    const int g = l >> 4;                  // k-group
    const int c = l & 15;                  // A row / B col
    const int row = R0 + c;
    const long base = (long)row * F_IN + g * 8;
    const short* __restrict__ wfp = w1f + ((size_t)(s * NWIN) * 64 + l) * 8;

    short8v bf[NWIN];
#pragma unroll
    for (int wl = 0; wl < NWIN; ++wl)
        bf[wl] = *(const short8v*)(wfp + (size_t)wl * 512);

    float4u va[NWIN][2];
    if (bid != GB1 - 1) {                  // fast arm: unguarded
#pragma unroll
        for (int wl = 0; wl < NWIN; ++wl) {
            long kb = base + (long)(s * NWIN + wl) * 32;
            va[wl][0] = *(const float4u*)(x + kb);
            va[wl][1] = *(const float4u*)(x + kb + 4);
        }
    } else {                               // final tile: clamp flat index
#pragma unroll
        for (int wl = 0; wl < NWIN; ++wl) {
            long kb = base + (long)(s * NWIN + wl) * 32;
            if (kb > NTOT - 8) kb = NTOT - 8;
            va[wl][0] = *(const float4u*)(x + kb);
            va[wl][1] = *(const float4u*)(x + kb + 4);
        }
    }

    float4v acc = {0.f, 0.f, 0.f, 0.f};
#pragma unroll
    for (int wl = 0; wl < NWIN; ++wl) {
        short8v af;
#pragma unroll
        for (int i = 0; i < 4; ++i) af[i] = (short)f2bf(va[wl][0][i]);
#pragma unroll
        for (int i = 0; i < 4; ++i) af[4 + i] = (short)f2bf(va[wl][1][i]);
        acc = __builtin_amdgcn_mfma_f32_16x16x32_bf16(af, bf[wl], acc, 0, 0, 0);
    }

    // cross-wave K reduction (D map: col=l&15, row=4*(l>>4)+j — verified R6+)
#pragma unroll
    for (int j = 0; j < 4; ++j) red[s][l * 4 + j] = acc[j];
    __syncthreads();
    {
        int r = tid >> 4, cc = tid & 15;
        int idx = ((r >> 2) * 16 + cc) * 4 + (r & 3);
        float vv = red[0][idx] + red[1][idx] + red[2][idx] + red[3][idx];
        t1[(long)(R0 + r) * HID + cc] = vv;
    }
}

// ---------------- fill arm (noinline): XCD-private 8x1024 buckets -----------
__device__ __noinline__ void fill_arm(int fbid, const int* __restrict__ src,
                                      const int* __restrict__ dst,
                                      int* __restrict__ cnt, int* __restrict__ bkt) {
    const int p = blockIdx.x & 7;                    // blockIdx->XCD round-robin
    int i = fbid * 256 + threadIdx.x;                // exact: 3125*256 = 800k quads
    int4 s4 = ((const int4*)src)[i];
    int4 d4 = ((const int4*)dst)[i];
    unsigned b, dl; int pos;
    b = (unsigned)d4.x / NPBK; dl = (unsigned)d4.x - b * NPBK;
    pos = atomicAdd(&cnt[(p << 10) + b], 1);
    if (pos < BCAP2) bkt[((size_t)((p << 10) + b) << 9) + pos] = (int)((dl << 17) | (unsigned)s4.x);
    b = (unsigned)d4.y / NPBK; dl = (unsigned)d4.y - b * NPBK;
    pos = atomicAdd(&cnt[(p << 10) + b], 1);
    if (pos < BCAP2) bkt[((size_t)((p << 10) + b) << 9) + pos] = (int)((dl << 17) | (unsigned)s4.y);
    b = (unsigned)d4.z / NPBK; dl = (unsigned)d4.z - b * NPBK;
    pos = atomicAdd(&cnt[(p << 10) + b], 1);
    if (pos < BCAP2) bkt[((size_t)((p << 10) + b) << 9) + pos] = (int)((dl << 17) | (unsigned)s4.z);
    b = (unsigned)d4.w / NPBK; dl = (unsigned)d4.w - b * NPBK;
    pos = atomicAdd(&cnt[(p << 10) + b], 1);
    if (pos < BCAP2) bkt[((size_t)((p << 10) + b) << 9) + pos] = (int)((dl << 17) | (unsigned)s4.w);
}

// ---------------- fat1: gemm tiles (first) ++ bucket fill (tail) ------------
__global__ __launch_bounds__(256) void fat1_kernel(const float* __restrict__ x,
                                                   const short* __restrict__ w1f,
                                                   float* __restrict__ t1,
                                                   const int* __restrict__ src,
                                                   const int* __restrict__ dst,
                                                   int* __restrict__ cnt,
                                                   int* __restrict__ bkt) {
    const int bid = blockIdx.x;
    if (bid < GB1) gemm_arm(bid, x, w1f, t1);
    else           fill_arm(bid - GB1, src, dst, cnt, bkt);
}

// ---------------- agg1 + fused gemm2: LDS-CSR node-centric (R22-proven) -----
__global__ __launch_bounds__(256) void agg1f_kernel(const float* __restrict__ t1,
                                                    const int* __restrict__ cnt,
                                                    const int* __restrict__ bkt,
                                                    const float* __restrict__ b1,
                                                    const float* __restrict__ W2,
                                                    float* __restrict__ t2p) {
    __shared__ int els[4096];
    __shared__ int ecsr[4096];
    __shared__ int dcnt[128], doff[128], dcur[128];
    __shared__ int pbase[9];
    __shared__ float hl[NPBK][16];
    const int b = blockIdx.x;
    const int t = threadIdx.x;
    if (t == 0) {
        int s = 0;
        for (int p = 0; p < 8; ++p) {
            pbase[p] = s;
            int ne = cnt[(p << 10) + b]; if (ne > BCAP2) ne = BCAP2;
            s += ne;
        }
        pbase[8] = s;
    }
    if (t < 128) dcnt[t] = 0;
    __syncthreads();
    const int nt = pbase[8];
    for (int p = 0; p < 8; ++p) {
        int base0 = pbase[p], ne = pbase[p + 1] - base0;
        const int* __restrict__ bp = bkt + ((size_t)((p << 10) + b) << 9);
        for (int e = t; e < ne; e += 256) els[base0 + e] = bp[e];
    }
    __syncthreads();
    for (int e = t; e < nt; e += 256) atomicAdd(&dcnt[els[e] >> 17], 1);
    __syncthreads();
    if (t < 128) doff[t] = dcnt[t];
    __syncthreads();
    for (int d = 1; d < 128; d <<= 1) {
        int add = (t < 128 && t >= d) ? doff[t - d] : 0;
        __syncthreads();
        if (t < 128) doff[t] += add;
        __syncthreads();
    }
    if (t < 128) dcur[t] = doff[t] - dcnt[t];        // exclusive offsets
    __syncthreads();
    for (int e = t; e < nt; e += 256) {
        int v = els[e];
        int pos = atomicAdd(&dcur[v >> 17], 1);
        ecsr[pos] = v & SRCM;
    }
    __syncthreads();
    const int nbase = b * NPBK;
    {
        int q = t & 3;
        for (int nl = t >> 2; nl < NPBK; nl += 64) {
            int node = nbase + nl;
            if (node < N_NODES) {
                int o = doff[nl] - dcnt[nl];
                int d = dcnt[nl];
                float4 a = *(const float4*)(t1 + ((size_t)node * 16 + q * 4));
                float4 bb = *(const float4*)(b1 + q * 4);
                a.x += bb.x; a.y += bb.y; a.z += bb.z; a.w += bb.w;
                for (int e = 0; e < d; ++e) {
                    int s = ecsr[o + e];
                    float4 v = *(const float4*)(t1 + ((size_t)s * 16 + q * 4));
                    a.x += v.x; a.y += v.y; a.z += v.z; a.w += v.w;
                }
                float4 r = {fmaxf(a.x, 0.f), fmaxf(a.y, 0.f),
                            fmaxf(a.z, 0.f), fmaxf(a.w, 0.f)};
                *(float4*)(&hl[nl][q * 4]) = r;
            }
        }
    }
    __syncthreads();
    for (int idx = t; idx < NPBK * 8; idx += 256) {
        int ln = idx >> 3, c = idx & 7;
        int node = nbase + ln;
        if (node < N_NODES) {
            float a = 0.f;
            if (c < N_CLS) {
#pragma unroll
                for (int j = 0; j < HID; ++j) a = fmaf(hl[ln][j], W2[j * N_CLS + c], a);
            }
            t2p[(size_t)node * 8 + c] = a;
        }
    }
}

// ---------------- agg2: LDS-CSR node-centric (R22-proven) ----------------
__global__ __launch_bounds__(256) void agg2_kernel(const float* __restrict__ t2p,
                                                   const int* __restrict__ cnt,
                                                   const int* __restrict__ bkt,
                                                   const float* __restrict__ b2,
                                                   float* __restrict__ out) {
    __shared__ int els[4096];
    __shared__ int ecsr[4096];
    __shared__ int dcnt[128], doff[128], dcur[128];
    __shared__ int pbase[9];
    const int b = blockIdx.x;
    const int t = threadIdx.x;
    if (t == 0) {
        int s = 0;
        for (int p = 0; p < 8; ++p) {
            pbase[p] = s;
            int ne = cnt[(p << 10) + b]; if (ne > BCAP2) ne = BCAP2;
            s += ne;
        }
        pbase[8] = s;
    }
    if (t < 128) dcnt[t] = 0;
    __syncthreads();
    const int nt = pbase[8];
    for (int p = 0; p < 8; ++p) {
        int base0 = pbase[p], ne = pbase[p + 1] - base0;
        const int* __restrict__ bp = bkt + ((size_t)((p << 10) + b) << 9);
        for (int e = t; e < ne; e += 256) els[base0 + e] = bp[e];
    }
    __syncthreads();
    for (int e = t; e < nt; e += 256) atomicAdd(&dcnt[els[e] >> 17], 1);
    __syncthreads();
    if (t < 128) doff[t] = dcnt[t];
    __syncthreads();
    for (int d = 1; d < 128; d <<= 1) {
        int add = (t < 128 && t >= d) ? doff[t - d] : 0;
        __syncthreads();
        if (t < 128) doff[t] += add;
        __syncthreads();
    }
    if (t < 128) dcur[t] = doff[t] - dcnt[t];
    __syncthreads();
    for (int e = t; e < nt; e += 256) {
        int v = els[e];
        int pos = atomicAdd(&dcur[v >> 17], 1);
        ecsr[pos] = v & SRCM;
    }
    __syncthreads();
    const int nbase = b * NPBK;
    {
        int q = t & 1;
        for (int nl = t >> 1; nl < NPBK; nl += 128) {
            int node = nbase + nl;
            if (node < N_NODES) {
                int o = doff[nl] - dcnt[nl];
                int d = dcnt[nl];
                float4 a = *(const float4*)(t2p + ((size_t)node * 8 + q * 4));
                if (q == 0) {
                    a.x += b2[0]; a.y += b2[1]; a.z += b2[2]; a.w += b2[3];
                } else {
                    a.x += b2[4]; a.y += b2[5]; a.z += b2[6];
                }
                for (int e = 0; e < d; ++e) {
                    int s = ecsr[o + e];
                    float4 v = *(const float4*)(t2p + ((size_t)s * 8 + q * 4));
                    a.x += v.x; a.y += v.y; a.z += v.z; a.w += v.w;
                }
                float* op = out + (size_t)node * 7 + q * 4;
                op[0] = a.x; op[1] = a.y; op[2] = a.z;
                if (q == 0) op[3] = a.w;
            }
        }
    }
}

// ---------------- launch ----------------

extern "C" void kernel_launch(void* const* d_in, const int* in_sizes, int n_in,
                              void* d_out, int out_size, void* d_ws, size_t ws_size,
                              hipStream_t stream) {
    const float* x  = (const float*)d_in[0];
    const int*   ei = (const int*)d_in[1];
    const float* W1 = (const float*)d_in[2];
    const float* b1 = (const float*)d_in[3];
    const float* W2 = (const float*)d_in[4];
    const float* b2 = (const float*)d_in[5];
    const int* src = ei;
    const int* dst = ei + N_EDGES;
    float* out = (float*)d_out;

    char* w = (char*)d_ws;
    float* t1  = (float*)w;  w += (size_t)N_NODES * HID * sizeof(float);
    float* t2p = (float*)w;  w += (size_t)N_NODES * 8 * sizeof(float);
    short* w1f = (short*)w;  w += (size_t)NWINT * 64 * 8 * sizeof(short);
    int* cnt   = (int*)w;    w += (size_t)8 * NBKT * sizeof(int);
    int* bkt   = (int*)w;    w += (size_t)8 * NBKT * BCAP2 * sizeof(int);

    hipMemsetAsync(cnt, 0, (size_t)8 * NBKT * sizeof(int), stream);
    prep_w1_kernel<<<NWINT, 64, 0, stream>>>(W1, w1f);

    // gemm (first) ++ bucket fill (tail-overlapped), noinline-isolated arms
    fat1_kernel<<<GB1 + QBLK, 256, 0, stream>>>(x, w1f, t1, src, dst, cnt, bkt);

    agg1f_kernel<<<NBKT, 256, 0, stream>>>(t1, cnt, bkt, b1, W2, t2p);
    agg2_kernel<<<NBKT, 256, 0, stream>>>(t2p, cnt, bkt, b2, out);
}

// Round 25
// 299.081 us; speedup vs baseline: 4.0532x; 1.1488x over previous
//
#include <hip/hip_runtime.h>

#define N_NODES 100000
#define N_EDGES 3200000
#define F_IN    1433
#define HID     16
#define N_CLS   7
#define NWINT   48                                   // K windows of 32 (K padded to 1536)
#define NWIN    12                                   // windows per wave (4 waves)
#define GB1     (N_NODES / 16)                       // 6250 gemm tiles
#define QBLK    (N_EDGES / 4 / 256)                  // 3125 fill blocks (exact quads)
#define NTOT    ((long)N_NODES * F_IN)               // 143,300,000
#define NBKT    1024                                 // buckets
#define NPBK    98                                   // nodes per bucket (1024*98=100352)
#define BCAP2   512                                  // cap per (xcd,bucket); mean 391 +6σ
#define SRCM    0x1FFFF                              // 17-bit src mask

typedef __attribute__((ext_vector_type(8))) short short8v;
typedef __attribute__((ext_vector_type(4))) float float4v;
typedef float float4u __attribute__((ext_vector_type(4), aligned(4)));  // dword-aligned dwordx4

__device__ __forceinline__ unsigned short f2bf(float f) {
    unsigned u = __float_as_uint(f);
    u += 0x7fffu + ((u >> 16) & 1u);                 // RNE
    return (unsigned short)(u >> 16);
}

// ---------------- prep: pre-swizzled bf16 W1 fragments (zero past F_IN) -----
__global__ void prep_w1_kernel(const float* __restrict__ W1, short* __restrict__ w1f) {
    int w = blockIdx.x;
    int l = threadIdx.x;
    int col = l & 15;
    int kb = w * 32 + (l >> 4) * 8;
    short8v f;
#pragma unroll
    for (int i = 0; i < 8; ++i) {
        int k = kb + i;
        float v = (k < F_IN) ? W1[k * HID + col] : 0.f;
        f[i] = (short)f2bf(v);
    }
    *(short8v*)(w1f + ((size_t)w * 64 + l) * 8) = f;
}

// ---------------- gemm arm (noinline: isolated codegen, R19-collapse guard) -
// va[] preloaded straight-line (array -> loads can't sink; R24-proven depth).
// bf STREAMED per window from L2-hot w1f (48KB): frees 48 VGPR -> higher
// occupancy (R12/R13 law: this gemm's BW = waves x in-flight loads).
__device__ __noinline__ void gemm_arm(int bid, const float* __restrict__ x,
                                      const short* __restrict__ w1f,
                                      float* __restrict__ t1) {
    __shared__ float red[4][256];
    const int tid = threadIdx.x;
    const int s = tid >> 6;                // wave / K-slice
    const int l = tid & 63;                // lane
    const int R0 = bid * 16;
    const int g = l >> 4;                  // k-group
    const int c = l & 15;                  // A row / B col
    const int row = R0 + c;
    const long base = (long)row * F_IN + g * 8;
    const short* __restrict__ wfp = w1f + ((size_t)(s * NWIN) * 64 + l) * 8;

    float4u va[NWIN][2];
    if (bid != GB1 - 1) {                  // fast arm: unguarded
#pragma unroll
        for (int wl = 0; wl < NWIN; ++wl) {
            long kb = base + (long)(s * NWIN + wl) * 32;
            va[wl][0] = *(const float4u*)(x + kb);
            va[wl][1] = *(const float4u*)(x + kb + 4);
        }
    } else {                               // final tile: clamp flat index
#pragma unroll
        for (int wl = 0; wl < NWIN; ++wl) {
            long kb = base + (long)(s * NWIN + wl) * 32;
            if (kb > NTOT - 8) kb = NTOT - 8;
            va[wl][0] = *(const float4u*)(x + kb);
            va[wl][1] = *(const float4u*)(x + kb + 4);
        }
    }

    float4v acc = {0.f, 0.f, 0.f, 0.f};
#pragma unroll
    for (int wl = 0; wl < NWIN; ++wl) {
        short8v bfv = *(const short8v*)(wfp + (size_t)wl * 512);  // L2-hot
        short8v af;
#pragma unroll
        for (int i = 0; i < 4; ++i) af[i] = (short)f2bf(va[wl][0][i]);
#pragma unroll
        for (int i = 0; i < 4; ++i) af[4 + i] = (short)f2bf(va[wl][1][i]);
        acc = __builtin_amdgcn_mfma_f32_16x16x32_bf16(af, bfv, acc, 0, 0, 0);
    }

    // cross-wave K reduction (D map: col=l&15, row=4*(l>>4)+j — verified R6+)
#pragma unroll
    for (int j = 0; j < 4; ++j) red[s][l * 4 + j] = acc[j];
    __syncthreads();
    {
        int r = tid >> 4, cc = tid & 15;
        int idx = ((r >> 2) * 16 + cc) * 4 + (r & 3);
        float vv = red[0][idx] + red[1][idx] + red[2][idx] + red[3][idx];
        t1[(long)(R0 + r) * HID + cc] = vv;
    }
}

// ---------------- fill arm (noinline): XCD-private 8x1024 buckets -----------
__device__ __noinline__ void fill_arm(int fbid, const int* __restrict__ src,
                                      const int* __restrict__ dst,
                                      int* __restrict__ cnt, int* __restrict__ bkt) {
    const int p = blockIdx.x & 7;                    // blockIdx->XCD round-robin
    int i = fbid * 256 + threadIdx.x;                // exact: 3125*256 = 800k quads
    int4 s4 = ((const int4*)src)[i];
    int4 d4 = ((const int4*)dst)[i];
    unsigned b, dl; int pos;
    b = (unsigned)d4.x / NPBK; dl = (unsigned)d4.x - b * NPBK;
    pos = atomicAdd(&cnt[(p << 10) + b], 1);
    if (pos < BCAP2) bkt[((size_t)((p << 10) + b) << 9) + pos] = (int)((dl << 17) | (unsigned)s4.x);
    b = (unsigned)d4.y / NPBK; dl = (unsigned)d4.y - b * NPBK;
    pos = atomicAdd(&cnt[(p << 10) + b], 1);
    if (pos < BCAP2) bkt[((size_t)((p << 10) + b) << 9) + pos] = (int)((dl << 17) | (unsigned)s4.y);
    b = (unsigned)d4.z / NPBK; dl = (unsigned)d4.z - b * NPBK;
    pos = atomicAdd(&cnt[(p << 10) + b], 1);
    if (pos < BCAP2) bkt[((size_t)((p << 10) + b) << 9) + pos] = (int)((dl << 17) | (unsigned)s4.z);
    b = (unsigned)d4.w / NPBK; dl = (unsigned)d4.w - b * NPBK;
    pos = atomicAdd(&cnt[(p << 10) + b], 1);
    if (pos < BCAP2) bkt[((size_t)((p << 10) + b) << 9) + pos] = (int)((dl << 17) | (unsigned)s4.w);
}

// ---------------- fat1: gemm ++ fill INTERLEAVED 2:1 ------------------------
// Grid = 3*QBLK = 9375. bid%3==2 -> fill (3125 blocks, spread THROUGHOUT the
// gemm so atomics hide under gemm BW at all times, not just the drain; fill
// is only ~67MB so no R14-style thrash). Else gemm, gid = bid - (bid+1)/3.
// bid&7 over bids ≡2 (mod 3) cycles all 8 XCDs (gcd(3,8)=1) -> privacy holds.
__global__ __launch_bounds__(256) void fat1_kernel(const float* __restrict__ x,
                                                   const short* __restrict__ w1f,
                                                   float* __restrict__ t1,
                                                   const int* __restrict__ src,
                                                   const int* __restrict__ dst,
                                                   int* __restrict__ cnt,
                                                   int* __restrict__ bkt) {
    const int bid = blockIdx.x;
    if (bid % 3 == 2) fill_arm((bid - 2) / 3, src, dst, cnt, bkt);
    else              gemm_arm(bid - (bid + 1) / 3, x, w1f, t1);
}

// ---------------- agg1 + fused gemm2: LDS-CSR node-centric (R22-proven) -----
__global__ __launch_bounds__(256) void agg1f_kernel(const float* __restrict__ t1,
                                                    const int* __restrict__ cnt,
                                                    const int* __restrict__ bkt,
                                                    const float* __restrict__ b1,
                                                    const float* __restrict__ W2,
                                                    float* __restrict__ t2p) {
    __shared__ int els[4096];
    __shared__ int ecsr[4096];
    __shared__ int dcnt[128], doff[128], dcur[128];
    __shared__ int pbase[9];
    __shared__ float hl[NPBK][16];
    const int b = blockIdx.x;
    const int t = threadIdx.x;
    if (t == 0) {
        int s = 0;
        for (int p = 0; p < 8; ++p) {
            pbase[p] = s;
            int ne = cnt[(p << 10) + b]; if (ne > BCAP2) ne = BCAP2;
            s += ne;
        }
        pbase[8] = s;
    }
    if (t < 128) dcnt[t] = 0;
    __syncthreads();
    const int nt = pbase[8];
    for (int p = 0; p < 8; ++p) {
        int base0 = pbase[p], ne = pbase[p + 1] - base0;
        const int* __restrict__ bp = bkt + ((size_t)((p << 10) + b) << 9);
        for (int e = t; e < ne; e += 256) els[base0 + e] = bp[e];
    }
    __syncthreads();
    for (int e = t; e < nt; e += 256) atomicAdd(&dcnt[els[e] >> 17], 1);
    __syncthreads();
    if (t < 128) doff[t] = dcnt[t];
    __syncthreads();
    for (int d = 1; d < 128; d <<= 1) {
        int add = (t < 128 && t >= d) ? doff[t - d] : 0;
        __syncthreads();
        if (t < 128) doff[t] += add;
        __syncthreads();
    }
    if (t < 128) dcur[t] = doff[t] - dcnt[t];        // exclusive offsets
    __syncthreads();
    for (int e = t; e < nt; e += 256) {
        int v = els[e];
        int pos = atomicAdd(&dcur[v >> 17], 1);
        ecsr[pos] = v & SRCM;
    }
    __syncthreads();
    const int nbase = b * NPBK;
    {
        int q = t & 3;
        for (int nl = t >> 2; nl < NPBK; nl += 64) {
            int node = nbase + nl;
            if (node < N_NODES) {
                int o = doff[nl] - dcnt[nl];
                int d = dcnt[nl];
                float4 a = *(const float4*)(t1 + ((size_t)node * 16 + q * 4));
                float4 bb = *(const float4*)(b1 + q * 4);
                a.x += bb.x; a.y += bb.y; a.z += bb.z; a.w += bb.w;
                for (int e = 0; e < d; ++e) {
                    int s = ecsr[o + e];
                    float4 v = *(const float4*)(t1 + ((size_t)s * 16 + q * 4));
                    a.x += v.x; a.y += v.y; a.z += v.z; a.w += v.w;
                }
                float4 r = {fmaxf(a.x, 0.f), fmaxf(a.y, 0.f),
                            fmaxf(a.z, 0.f), fmaxf(a.w, 0.f)};
                *(float4*)(&hl[nl][q * 4]) = r;
            }
        }
    }
    __syncthreads();
    for (int idx = t; idx < NPBK * 8; idx += 256) {
        int ln = idx >> 3, c = idx & 7;
        int node = nbase + ln;
        if (node < N_NODES) {
            float a = 0.f;
            if (c < N_CLS) {
#pragma unroll
                for (int j = 0; j < HID; ++j) a = fmaf(hl[ln][j], W2[j * N_CLS + c], a);
            }
            t2p[(size_t)node * 8 + c] = a;
        }
    }
}

// ---------------- agg2: LDS-CSR node-centric (R22-proven) ----------------
__global__ __launch_bounds__(256) void agg2_kernel(const float* __restrict__ t2p,
                                                   const int* __restrict__ cnt,
                                                   const int* __restrict__ bkt,
                                                   const float* __restrict__ b2,
                                                   float* __restrict__ out) {
    __shared__ int els[4096];
    __shared__ int ecsr[4096];
    __shared__ int dcnt[128], doff[128], dcur[128];
    __shared__ int pbase[9];
    const int b = blockIdx.x;
    const int t = threadIdx.x;
    if (t == 0) {
        int s = 0;
        for (int p = 0; p < 8; ++p) {
            pbase[p] = s;
            int ne = cnt[(p << 10) + b]; if (ne > BCAP2) ne = BCAP2;
            s += ne;
        }
        pbase[8] = s;
    }
    if (t < 128) dcnt[t] = 0;
    __syncthreads();
    const int nt = pbase[8];
    for (int p = 0; p < 8; ++p) {
        int base0 = pbase[p], ne = pbase[p + 1] - base0;
        const int* __restrict__ bp = bkt + ((size_t)((p << 10) + b) << 9);
        for (int e = t; e < ne; e += 256) els[base0 + e] = bp[e];
    }
    __syncthreads();
    for (int e = t; e < nt; e += 256) atomicAdd(&dcnt[els[e] >> 17], 1);
    __syncthreads();
    if (t < 128) doff[t] = dcnt[t];
    __syncthreads();
    for (int d = 1; d < 128; d <<= 1) {
        int add = (t < 128 && t >= d) ? doff[t - d] : 0;
        __syncthreads();
        if (t < 128) doff[t] += add;
        __syncthreads();
    }
    if (t < 128) dcur[t] = doff[t] - dcnt[t];
    __syncthreads();
    for (int e = t; e < nt; e += 256) {
        int v = els[e];
        int pos = atomicAdd(&dcur[v >> 17], 1);
        ecsr[pos] = v & SRCM;
    }
    __syncthreads();
    const int nbase = b * NPBK;
    {
        int q = t & 1;
        for (int nl = t >> 1; nl < NPBK; nl += 128) {
            int node = nbase + nl;
            if (node < N_NODES) {
                int o = doff[nl] - dcnt[nl];
                int d = dcnt[nl];
                float4 a = *(const float4*)(t2p + ((size_t)node * 8 + q * 4));
                if (q == 0) {
                    a.x += b2[0]; a.y += b2[1]; a.z += b2[2]; a.w += b2[3];
                } else {
                    a.x += b2[4]; a.y += b2[5]; a.z += b2[6];
                }
                for (int e = 0; e < d; ++e) {
                    int s = ecsr[o + e];
                    float4 v = *(const float4*)(t2p + ((size_t)s * 8 + q * 4));
                    a.x += v.x; a.y += v.y; a.z += v.z; a.w += v.w;
                }
                float* op = out + (size_t)node * 7 + q * 4;
                op[0] = a.x; op[1] = a.y; op[2] = a.z;
                if (q == 0) op[3] = a.w;
            }
        }
    }
}

// ---------------- launch ----------------

extern "C" void kernel_launch(void* const* d_in, const int* in_sizes, int n_in,
                              void* d_out, int out_size, void* d_ws, size_t ws_size,
                              hipStream_t stream) {
    const float* x  = (const float*)d_in[0];
    const int*   ei = (const int*)d_in[1];
    const float* W1 = (const float*)d_in[2];
    const float* b1 = (const float*)d_in[3];
    const float* W2 = (const float*)d_in[4];
    const float* b2 = (const float*)d_in[5];
    const int* src = ei;
    const int* dst = ei + N_EDGES;
    float* out = (float*)d_out;

    char* w = (char*)d_ws;
    float* t1  = (float*)w;  w += (size_t)N_NODES * HID * sizeof(float);
    float* t2p = (float*)w;  w += (size_t)N_NODES * 8 * sizeof(float);
    short* w1f = (short*)w;  w += (size_t)NWINT * 64 * 8 * sizeof(short);
    int* cnt   = (int*)w;    w += (size_t)8 * NBKT * sizeof(int);
    int* bkt   = (int*)w;    w += (size_t)8 * NBKT * BCAP2 * sizeof(int);

    hipMemsetAsync(cnt, 0, (size_t)8 * NBKT * sizeof(int), stream);
    prep_w1_kernel<<<NWINT, 64, 0, stream>>>(W1, w1f);

    // gemm ++ fill interleaved 2:1 (fill spread through the whole gemm)
    fat1_kernel<<<GB1 + QBLK, 256, 0, stream>>>(x, w1f, t1, src, dst, cnt, bkt);

    agg1f_kernel<<<NBKT, 256, 0, stream>>>(t1, cnt, bkt, b1, W2, t2p);
    agg2_kernel<<<NBKT, 256, 0, stream>>>(t2p, cnt, bkt, b2, out);
}

// Round 27
// 287.913 us; speedup vs baseline: 4.2104x; 1.0388x over previous
//
#include <hip/hip_runtime.h>

#define N_NODES 100000
#define N_EDGES 3200000
#define F_IN    1433
#define HID     16
#define N_CLS   7
#define NWINT   48                                   // K windows of 32 (K padded to 1536)
#define NWIN    12                                   // windows per wave (4 waves)
#define GB1     (N_NODES / 16)                       // 6250 gemm tiles
#define QBLK    (N_EDGES / 4 / 256)                  // 3125 fill blocks (exact quads)
#define NTOT    ((long)N_NODES * F_IN)               // 143,300,000
#define NBKT    1024                                 // buckets
#define NPBK    98                                   // nodes per bucket (1024*98=100352)
#define BCAP2   512                                  // cap per (xcd,bucket); mean 391 +6σ
#define SRCM    0x1FFFF                              // 17-bit src mask

typedef __attribute__((ext_vector_type(8))) short short8v;
typedef __attribute__((ext_vector_type(4))) float float4v;

typedef const __attribute__((address_space(1))) unsigned* gptr_t;
typedef __attribute__((address_space(3))) unsigned* lptr_t;

__device__ __forceinline__ unsigned short f2bf(float f) {
    unsigned u = __float_as_uint(f);
    u += 0x7fffu + ((u >> 16) & 1u);                 // RNE
    return (unsigned short)(u >> 16);
}

__device__ __forceinline__ void gll16(const float* g, float* lds) {
    // address-space casts must go through integer (reinterpret_cast is rejected)
    gptr_t gp = (gptr_t)(unsigned long long)(uintptr_t)g;
    lptr_t lp = (lptr_t)(unsigned)(uintptr_t)lds;    // LDS addr fits 32 bits
    __builtin_amdgcn_global_load_lds(gp, lp, 16, 0, 0);
}

// ---------------- prep: pre-swizzled bf16 W1 fragments (zero past F_IN) -----
__global__ void prep_w1_kernel(const float* __restrict__ W1, short* __restrict__ w1f) {
    int w = blockIdx.x;
    int l = threadIdx.x;
    int col = l & 15;
    int kb = w * 32 + (l >> 4) * 8;
    short8v f;
#pragma unroll
    for (int i = 0; i < 8; ++i) {
        int k = kb + i;
        float v = (k < F_IN) ? W1[k * HID + col] : 0.f;
        f[i] = (short)f2bf(v);
    }
    *(short8v*)(w1f + ((size_t)w * 64 + l) * 8) = f;
}

// ---------------- gemm arm: global_load_lds double-buffered -----------------
// Staging via global_load_lds (VGPR-free in-flight; the reg-staging ceiling
// ~3TB/s was VGPR-bound). Window = 16 rows x 32 floats = 128 chunks of 16B,
// stored at SWIZZLED position p = CH ^ ((CH>>3)&7) via pre-swizzled GLOBAL
// source (LDS dest must stay linear, m104): staging lane l instr j holds
// chunk with row = j*8 + (l>>3), q = (l&7)^((l>>3)&7). Reads (lane g,c:
// chunks c*8+2g{,+1} at p = c*8 + ((2g+j')^(c&7))) become 2-way (free) vs
// 16-way unswizzled. vmcnt(2) + sched_barrier fence per window (rule #18).
__device__ __noinline__ void gemm_arm(int gid, const float* __restrict__ x,
                                      const short* __restrict__ w1f,
                                      float* __restrict__ t1) {
    __shared__ float xs[4][2][512];        // per-wave double buffer, 2KB each
    __shared__ float red[4][256];
    const int tid = threadIdx.x;
    const int s = tid >> 6;                // wave / K-slice
    const int l = tid & 63;                // lane
    const int R0 = gid * 16;
    const int g = l >> 4;                  // k-group
    const int c = l & 15;                  // A row / B col
    const short* __restrict__ wfp = w1f + ((size_t)(s * NWIN) * 64 + l) * 8;

    short8v bf[NWIN];                      // preloaded -> vmcnt counts only x
#pragma unroll
    for (int wl = 0; wl < NWIN; ++wl)
        bf[wl] = *(const short8v*)(wfp + (size_t)wl * 512);

    // staging lane constants (fixed across windows)
    const int lr = l >> 3;                 // 0..7
    const int q = (l & 7) ^ lr;            // swizzled chunk-within-row
    const long gb0 = (long)(R0 + lr) * F_IN + q * 4;
    const long gb1 = (long)(R0 + 8 + lr) * F_IN + q * 4;
    const bool last = (gid == GB1 - 1);
    const int kbase = s * NWIN * 32;

    // read-side LDS byte offsets (within a buffer)
    const int p0f = (c * 8 + ((2 * g) ^ (c & 7))) * 16;
    const int p1  = (c * 8 + ((2 * g + 1) ^ (c & 7))) * 16;

    // prologue: window 0 -> buf 0
    {
        long gi0 = gb0 + kbase, gi1 = gb1 + kbase;
        if (last) { if (gi0 > NTOT - 4) gi0 = NTOT - 4; if (gi1 > NTOT - 4) gi1 = NTOT - 4; }
        gll16(x + gi0, &xs[s][0][0]);
        gll16(x + gi1, &xs[s][0][256]);
    }

    float4v acc = {0.f, 0.f, 0.f, 0.f};
#pragma unroll
    for (int wl = 0; wl < NWIN; ++wl) {
        if (wl + 1 < NWIN) {
            int buf = (wl + 1) & 1;
            long kw = kbase + (long)(wl + 1) * 32;
            long gi0 = gb0 + kw, gi1 = gb1 + kw;
            if (last) { if (gi0 > NTOT - 4) gi0 = NTOT - 4; if (gi1 > NTOT - 4) gi1 = NTOT - 4; }
            gll16(x + gi0, &xs[s][buf][0]);
            gll16(x + gi1, &xs[s][buf][256]);
            asm volatile("s_waitcnt vmcnt(2)" ::: "memory");
        } else {
            asm volatile("s_waitcnt vmcnt(0)" ::: "memory");
        }
        __builtin_amdgcn_sched_barrier(0);
        const char* bb = (const char*)&xs[s][wl & 1][0];
        float4 lo = *(const float4*)(bb + p0f);
        float4 hi = *(const float4*)(bb + p1);
        short8v af;
        af[0] = (short)f2bf(lo.x); af[1] = (short)f2bf(lo.y);
        af[2] = (short)f2bf(lo.z); af[3] = (short)f2bf(lo.w);
        af[4] = (short)f2bf(hi.x); af[5] = (short)f2bf(hi.y);
        af[6] = (short)f2bf(hi.z); af[7] = (short)f2bf(hi.w);
        acc = __builtin_amdgcn_mfma_f32_16x16x32_bf16(af, bf[wl], acc, 0, 0, 0);
    }

    // cross-wave K reduction (D map: col=l&15, row=4*(l>>4)+j — verified R6+)
#pragma unroll
    for (int j = 0; j < 4; ++j) red[s][l * 4 + j] = acc[j];
    __syncthreads();
    {
        int r = tid >> 4, cc = tid & 15;
        int idx = ((r >> 2) * 16 + cc) * 4 + (r & 3);
        float vv = red[0][idx] + red[1][idx] + red[2][idx] + red[3][idx];
        t1[(long)(R0 + r) * HID + cc] = vv;
    }
}

// ---------------- fill arm (noinline): XCD-private 8x1024 buckets -----------
__device__ __noinline__ void fill_arm(int fbid, const int* __restrict__ src,
                                      const int* __restrict__ dst,
                                      int* __restrict__ cnt, int* __restrict__ bkt) {
    const int p = blockIdx.x & 7;                    // blockIdx->XCD round-robin
    int i = fbid * 256 + threadIdx.x;                // exact: 3125*256 = 800k quads
    int4 s4 = ((const int4*)src)[i];
    int4 d4 = ((const int4*)dst)[i];
    unsigned b, dl; int pos;
    b = (unsigned)d4.x / NPBK; dl = (unsigned)d4.x - b * NPBK;
    pos = atomicAdd(&cnt[(p << 10) + b], 1);
    if (pos < BCAP2) bkt[((size_t)((p << 10) + b) << 9) + pos] = (int)((dl << 17) | (unsigned)s4.x);
    b = (unsigned)d4.y / NPBK; dl = (unsigned)d4.y - b * NPBK;
    pos = atomicAdd(&cnt[(p << 10) + b], 1);
    if (pos < BCAP2) bkt[((size_t)((p << 10) + b) << 9) + pos] = (int)((dl << 17) | (unsigned)s4.y);
    b = (unsigned)d4.z / NPBK; dl = (unsigned)d4.z - b * NPBK;
    pos = atomicAdd(&cnt[(p << 10) + b], 1);
    if (pos < BCAP2) bkt[((size_t)((p << 10) + b) << 9) + pos] = (int)((dl << 17) | (unsigned)s4.z);
    b = (unsigned)d4.w / NPBK; dl = (unsigned)d4.w - b * NPBK;
    pos = atomicAdd(&cnt[(p << 10) + b], 1);
    if (pos < BCAP2) bkt[((size_t)((p << 10) + b) << 9) + pos] = (int)((dl << 17) | (unsigned)s4.w);
}

// ---------------- fat1: gemm ++ fill INTERLEAVED 2:1 (R25-proven) -----------
__global__ __launch_bounds__(256) void fat1_kernel(const float* __restrict__ x,
                                                   const short* __restrict__ w1f,
                                                   float* __restrict__ t1,
                                                   const int* __restrict__ src,
                                                   const int* __restrict__ dst,
                                                   int* __restrict__ cnt,
                                                   int* __restrict__ bkt) {
    const int bid = blockIdx.x;
    if (bid % 3 == 2) fill_arm((bid - 2) / 3, src, dst, cnt, bkt);
    else              gemm_arm(bid - (bid + 1) / 3, x, w1f, t1);
}

// ---------------- agg1 + fused gemm2: LDS-CSR node-centric (R22-proven) -----
__global__ __launch_bounds__(256) void agg1f_kernel(const float* __restrict__ t1,
                                                    const int* __restrict__ cnt,
                                                    const int* __restrict__ bkt,
                                                    const float* __restrict__ b1,
                                                    const float* __restrict__ W2,
                                                    float* __restrict__ t2p) {
    __shared__ int els[4096];
    __shared__ int ecsr[4096];
    __shared__ int dcnt[128], doff[128], dcur[128];
    __shared__ int pbase[9];
    __shared__ float hl[NPBK][16];
    const int b = blockIdx.x;
    const int t = threadIdx.x;
    if (t == 0) {
        int s = 0;
        for (int p = 0; p < 8; ++p) {
            pbase[p] = s;
            int ne = cnt[(p << 10) + b]; if (ne > BCAP2) ne = BCAP2;
            s += ne;
        }
        pbase[8] = s;
    }
    if (t < 128) dcnt[t] = 0;
    __syncthreads();
    const int nt = pbase[8];
    for (int p = 0; p < 8; ++p) {
        int base0 = pbase[p], ne = pbase[p + 1] - base0;
        const int* __restrict__ bp = bkt + ((size_t)((p << 10) + b) << 9);
        for (int e = t; e < ne; e += 256) els[base0 + e] = bp[e];
    }
    __syncthreads();
    for (int e = t; e < nt; e += 256) atomicAdd(&dcnt[els[e] >> 17], 1);
    __syncthreads();
    if (t < 128) doff[t] = dcnt[t];
    __syncthreads();
    for (int d = 1; d < 128; d <<= 1) {
        int add = (t < 128 && t >= d) ? doff[t - d] : 0;
        __syncthreads();
        if (t < 128) doff[t] += add;
        __syncthreads();
    }
    if (t < 128) dcur[t] = doff[t] - dcnt[t];        // exclusive offsets
    __syncthreads();
    for (int e = t; e < nt; e += 256) {
        int v = els[e];
        int pos = atomicAdd(&dcur[v >> 17], 1);
        ecsr[pos] = v & SRCM;
    }
    __syncthreads();
    const int nbase = b * NPBK;
    {
        int q = t & 3;
        for (int nl = t >> 2; nl < NPBK; nl += 64) {
            int node = nbase + nl;
            if (node < N_NODES) {
                int o = doff[nl] - dcnt[nl];
                int d = dcnt[nl];
                float4 a = *(const float4*)(t1 + ((size_t)node * 16 + q * 4));
                float4 bb = *(const float4*)(b1 + q * 4);
                a.x += bb.x; a.y += bb.y; a.z += bb.z; a.w += bb.w;
                for (int e = 0; e < d; ++e) {
                    int s = ecsr[o + e];
                    float4 v = *(const float4*)(t1 + ((size_t)s * 16 + q * 4));
                    a.x += v.x; a.y += v.y; a.z += v.z; a.w += v.w;
                }
                float4 r = {fmaxf(a.x, 0.f), fmaxf(a.y, 0.f),
                            fmaxf(a.z, 0.f), fmaxf(a.w, 0.f)};
                *(float4*)(&hl[nl][q * 4]) = r;
            }
        }
    }
    __syncthreads();
    for (int idx = t; idx < NPBK * 8; idx += 256) {
        int ln = idx >> 3, c = idx & 7;
        int node = nbase + ln;
        if (node < N_NODES) {
            float a = 0.f;
            if (c < N_CLS) {
#pragma unroll
                for (int j = 0; j < HID; ++j) a = fmaf(hl[ln][j], W2[j * N_CLS + c], a);
            }
            t2p[(size_t)node * 8 + c] = a;
        }
    }
}

// ---------------- agg2: LDS-CSR node-centric (R22-proven) ----------------
__global__ __launch_bounds__(256) void agg2_kernel(const float* __restrict__ t2p,
                                                   const int* __restrict__ cnt,
                                                   const int* __restrict__ bkt,
                                                   const float* __restrict__ b2,
                                                   float* __restrict__ out) {
    __shared__ int els[4096];
    __shared__ int ecsr[4096];
    __shared__ int dcnt[128], doff[128], dcur[128];
    __shared__ int pbase[9];
    const int b = blockIdx.x;
    const int t = threadIdx.x;
    if (t == 0) {
        int s = 0;
        for (int p = 0; p < 8; ++p) {
            pbase[p] = s;
            int ne = cnt[(p << 10) + b]; if (ne > BCAP2) ne = BCAP2;
            s += ne;
        }
        pbase[8] = s;
    }
    if (t < 128) dcnt[t] = 0;
    __syncthreads();
    const int nt = pbase[8];
    for (int p = 0; p < 8; ++p) {
        int base0 = pbase[p], ne = pbase[p + 1] - base0;
        const int* __restrict__ bp = bkt + ((size_t)((p << 10) + b) << 9);
        for (int e = t; e < ne; e += 256) els[base0 + e] = bp[e];
    }
    __syncthreads();
    for (int e = t; e < nt; e += 256) atomicAdd(&dcnt[els[e] >> 17], 1);
    __syncthreads();
    if (t < 128) doff[t] = dcnt[t];
    __syncthreads();
    for (int d = 1; d < 128; d <<= 1) {
        int add = (t < 128 && t >= d) ? doff[t - d] : 0;
        __syncthreads();
        if (t < 128) doff[t] += add;
        __syncthreads();
    }
    if (t < 128) dcur[t] = doff[t] - dcnt[t];
    __syncthreads();
    for (int e = t; e < nt; e += 256) {
        int v = els[e];
        int pos = atomicAdd(&dcur[v >> 17], 1);
        ecsr[pos] = v & SRCM;
    }
    __syncthreads();
    const int nbase = b * NPBK;
    {
        int q = t & 1;
        for (int nl = t >> 1; nl < NPBK; nl += 128) {
            int node = nbase + nl;
            if (node < N_NODES) {
                int o = doff[nl] - dcnt[nl];
                int d = dcnt[nl];
                float4 a = *(const float4*)(t2p + ((size_t)node * 8 + q * 4));
                if (q == 0) {
                    a.x += b2[0]; a.y += b2[1]; a.z += b2[2]; a.w += b2[3];
                } else {
                    a.x += b2[4]; a.y += b2[5]; a.z += b2[6];
                }
                for (int e = 0; e < d; ++e) {
                    int s = ecsr[o + e];
                    float4 v = *(const float4*)(t2p + ((size_t)s * 8 + q * 4));
                    a.x += v.x; a.y += v.y; a.z += v.z; a.w += v.w;
                }
                float* op = out + (size_t)node * 7 + q * 4;
                op[0] = a.x; op[1] = a.y; op[2] = a.z;
                if (q == 0) op[3] = a.w;
            }
        }
    }
}

// ---------------- launch ----------------

extern "C" void kernel_launch(void* const* d_in, const int* in_sizes, int n_in,
                              void* d_out, int out_size, void* d_ws, size_t ws_size,
                              hipStream_t stream) {
    const float* x  = (const float*)d_in[0];
    const int*   ei = (const int*)d_in[1];
    const float* W1 = (const float*)d_in[2];
    const float* b1 = (const float*)d_in[3];
    const float* W2 = (const float*)d_in[4];
    const float* b2 = (const float*)d_in[5];
    const int* src = ei;
    const int* dst = ei + N_EDGES;
    float* out = (float*)d_out;

    char* w = (char*)d_ws;
    float* t1  = (float*)w;  w += (size_t)N_NODES * HID * sizeof(float);
    float* t2p = (float*)w;  w += (size_t)N_NODES * 8 * sizeof(float);
    short* w1f = (short*)w;  w += (size_t)NWINT * 64 * 8 * sizeof(short);
    int* cnt   = (int*)w;    w += (size_t)8 * NBKT * sizeof(int);
    int* bkt   = (int*)w;    w += (size_t)8 * NBKT * BCAP2 * sizeof(int);

    (void)hipMemsetAsync(cnt, 0, (size_t)8 * NBKT * sizeof(int), stream);
    prep_w1_kernel<<<NWINT, 64, 0, stream>>>(W1, w1f);

    // gemm (global_load_lds staged) ++ fill interleaved 2:1
    fat1_kernel<<<GB1 + QBLK, 256, 0, stream>>>(x, w1f, t1, src, dst, cnt, bkt);

    agg1f_kernel<<<NBKT, 256, 0, stream>>>(t1, cnt, bkt, b1, W2, t2p);
    agg2_kernel<<<NBKT, 256, 0, stream>>>(t2p, cnt, bkt, b2, out);
}